// Round 7
// baseline (349.878 us; speedup 1.0000x reference)
//
#include <hip/hip_runtime.h>
#include <math.h>

#define N_NODES 10000
#define B_SZ 4
#define SLOPE 0.01f
#define BN (B_SZ * N_NODES)
#define PADK 136   // ushorts per LDS C-row (272B, 16B-aligned)

typedef __attribute__((ext_vector_type(8))) short short8;
typedef __attribute__((ext_vector_type(4))) float float4v;

__device__ __forceinline__ unsigned short f2bf(float f) {
    unsigned u = __builtin_bit_cast(unsigned, f);
    u += 0x7fffu + ((u >> 16) & 1u);   // RNE
    return (unsigned short)(u >> 16);
}
__device__ __forceinline__ float bf2f(unsigned short s) {
    unsigned u = ((unsigned)s) << 16;
    return __builtin_bit_cast(float, u);
}
__device__ __forceinline__ float bflo(unsigned u) { return __builtin_bit_cast(float, u << 16); }
__device__ __forceinline__ float bfhi(unsigned u) { return __builtin_bit_cast(float, u & 0xffff0000u); }

// All activations batch-major: row index g = b*N_NODES + n.

// ---------------- fused setup: prep0 (vectorized x8) + wconv + init ----------------

__global__ __launch_bounds__(256) void setup_kernel(
    const float* __restrict__ strucEmb, const float* __restrict__ state,
    const float* __restrict__ Wns0, const float* __restrict__ bns0,
    const float* __restrict__ gatW, const float* __restrict__ W2,
    unsigned short* __restrict__ XS,
    unsigned short* __restrict__ whi, unsigned short* __restrict__ wlo,
    int* deg, int* cursor, float* state_emb)
{
    int bx = blockIdx.x, tid = threadIdx.x;
    if (bx < 2500) {
        int base = (bx * 256 + tid) * 8;       // element index, 8 per thread, same row g
        int g = base >> 7, d0 = base & 127;
        int n = g - (g / N_NODES) * N_NODES;
        float st = state[g];
        const float* se = strucEmb + (size_t)n * 128 + d0;
        const float* wp = Wns0 + d0;
        const float* bp = bns0 + d0;
        short8 v;
#pragma unroll
        for (int j = 0; j < 8; j++)
            v[j] = (short)f2bf(se[j] + st * wp[j] + bp[j]);
        *(short8*)(XS + base) = v;
    } else if (bx < 2756) {
        int i = (bx - 2500) * 256 + tid;     // 0..65535
        int w = i >> 14, rem = i & 16383;
        int k = rem >> 7, c = rem & 127;
        const float* src = (w < 3) ? (gatW + (size_t)w * 16384) : W2;
        float v = src[k * 128 + c];
        unsigned short h = f2bf(v);
        whi[w * 16384 + c * 128 + k] = h;
        wlo[w * 16384 + c * 128 + k] = f2bf(v - bf2f(h));
    } else {
        int i = (bx - 2756) * 256 + tid;
        if (i < N_NODES) { deg[i] = 0; cursor[i] = 0; }
        if (i < 512) state_emb[i] = 0.f;
    }
}

// ---------------- CSR build ----------------

__global__ __launch_bounds__(256) void hist_kernel(const int* __restrict__ dst, int Etot, int* deg) {
    int e = blockIdx.x * 256 + threadIdx.x;
    if (e < Etot) atomicAdd(&deg[dst[e]], 1);
}

__global__ __launch_bounds__(1024) void scan_kernel(const int* __restrict__ deg, int* __restrict__ rowOff) {
    __shared__ int wsum[16];
    int tid = threadIdx.x;
    int lane = tid & 63, wid = tid >> 6;
    int base = tid * 10;
    int v[10]; int tot = 0;
#pragma unroll
    for (int j = 0; j < 10; j++) {
        int idx = base + j;
        int d = (idx < N_NODES) ? deg[idx] : 0;
        tot += d; v[j] = tot;
    }
    int incl = tot;
    for (int off = 1; off < 64; off <<= 1) {
        int t = __shfl_up(incl, off, 64);
        if (lane >= off) incl += t;
    }
    if (lane == 63) wsum[wid] = incl;
    __syncthreads();
    if (wid == 0) {
        int wv = (lane < 16) ? wsum[lane] : 0;
        for (int off = 1; off < 16; off <<= 1) {
            int t = __shfl_up(wv, off, 64);
            if (lane >= off) wv += t;
        }
        if (lane < 16) wsum[lane] = wv;
    }
    __syncthreads();
    int waveoff = (wid > 0) ? wsum[wid - 1] : 0;
    int excl = waveoff + incl - tot;
    if (tid == 0) rowOff[0] = 0;
#pragma unroll
    for (int j = 0; j < 10; j++) {
        int idx = base + j;
        if (idx < N_NODES) rowOff[idx + 1] = excl + v[j];
    }
}

__global__ __launch_bounds__(256) void scatter_kernel(const int* __restrict__ src, const int* __restrict__ dst,
                                                      int Etot, const int* __restrict__ rowOff,
                                                      int* cursor, int* __restrict__ srcLst) {
    int e = blockIdx.x * 256 + threadIdx.x;
    if (e < Etot) {
        int d = dst[e];
        int pos = rowOff[d] + atomicAdd(&cursor[d], 1);
        srcLst[pos] = src[e];
    }
}

// ---------------- MFMA GEMM (GAT layer): H(bf16) = XS(bf16) @ W ; att dots ----------------

__global__ __launch_bounds__(256) void gemm_att_mfma(
    const unsigned short* __restrict__ XS,
    const unsigned short* __restrict__ WThi, const unsigned short* __restrict__ WTlo,
    const float* __restrict__ attS, const float* __restrict__ attD,
    unsigned short* __restrict__ Hout, float* __restrict__ aSrcP, float* __restrict__ aDstP)
{
    __shared__ __align__(16) unsigned short sCus[64 * PADK];
    __shared__ float sAs[128], sAd[128];
    __shared__ float sPart[64 * 8];

    int tid = threadIdx.x;
    int g0 = blockIdx.x * 64;
    int w = tid >> 6, lane = tid & 63;
    int quad = lane >> 4, mcol = lane & 15;

    if (tid < 128) { sAs[tid] = attS[tid]; sAd[tid] = attD[tid]; }

    float4v acc[4][2];
#pragma unroll
    for (int mt = 0; mt < 4; mt++)
#pragma unroll
        for (int nt = 0; nt < 2; nt++) acc[mt][nt] = (float4v){0.f, 0.f, 0.f, 0.f};

#pragma unroll 1
    for (int term = 0; term < 2; term++) {
        const unsigned short* WT = term ? WTlo : WThi;
        short8 Bf[4][2];
#pragma unroll
        for (int kc = 0; kc < 4; kc++)
#pragma unroll
            for (int nt = 0; nt < 2; nt++)
                Bf[kc][nt] = *(const short8*)(WT + (w * 32 + nt * 16 + mcol) * 128 + kc * 32 + quad * 8);
#pragma unroll
        for (int kc = 0; kc < 4; kc++) {
            short8 Aa[4];
#pragma unroll
            for (int mt = 0; mt < 4; mt++)
                Aa[mt] = *(const short8*)(XS + (size_t)(g0 + mt * 16 + mcol) * 128 + kc * 32 + quad * 8);
#pragma unroll
            for (int mt = 0; mt < 4; mt++)
#pragma unroll
                for (int nt = 0; nt < 2; nt++)
                    acc[mt][nt] = __builtin_amdgcn_mfma_f32_16x16x32_bf16(Aa[mt], Bf[kc][nt], acc[mt][nt], 0, 0, 0);
        }
    }

    __syncthreads();   // sAs/sAd visible

    float pp[16], pd[16];
#pragma unroll
    for (int r16 = 0; r16 < 16; r16++) { pp[r16] = 0.f; pd[r16] = 0.f; }
#pragma unroll
    for (int mt = 0; mt < 4; mt++)
#pragma unroll
        for (int nt = 0; nt < 2; nt++)
#pragma unroll
            for (int reg = 0; reg < 4; reg++) {
                int row = mt * 16 + quad * 4 + reg;   // C/D: col=lane&15, row=quad*4+reg
                int col = w * 32 + nt * 16 + mcol;
                float v = acc[mt][nt][reg];
                sCus[row * PADK + col] = f2bf(v);
                pp[mt * 4 + reg] += v * sAs[col];
                pd[mt * 4 + reg] += v * sAd[col];
            }
#pragma unroll
    for (int off = 1; off < 16; off <<= 1)
#pragma unroll
        for (int r16 = 0; r16 < 16; r16++) {
            pp[r16] += __shfl_xor(pp[r16], off);
            pd[r16] += __shfl_xor(pd[r16], off);
        }
    if (mcol == 0) {
#pragma unroll
        for (int r16 = 0; r16 < 16; r16++) {
            int row = (r16 >> 2) * 16 + quad * 4 + (r16 & 3);
            sPart[row * 8 + w * 2 + 0] = pp[r16];
            sPart[row * 8 + w * 2 + 1] = pd[r16];
        }
    }
    __syncthreads();

    for (int i = tid; i < 64 * 16; i += 256) {
        int r = i >> 4, c8 = i & 15;
        uint4 u = *(uint4*)(sCus + r * PADK + c8 * 8);
        *(uint4*)(Hout + (size_t)(g0 + r) * 128 + c8 * 8) = u;
    }
    if (tid < 64) {
        float s0 = sPart[tid * 8] + sPart[tid * 8 + 2] + sPart[tid * 8 + 4] + sPart[tid * 8 + 6];
        float s1 = sPart[tid * 8 + 1] + sPart[tid * 8 + 3] + sPart[tid * 8 + 5] + sPart[tid * 8 + 7];
        aSrcP[g0 + tid] = s0;
        aDstP[g0 + tid] = s1;
    }
}

// ---------------- fused softmax + aggregate, ALL 4 BATCHES per wave ----------------
// Grid 2500 blocks x 4 waves: wave w owns node n = bx*4+w for b=0..3. srcLst indices are
// batch-independent -> loaded once; the H gather issues 8 independent uint4 loads per step
// (2 j-slots x 4 batches) for latency hiding. Per-wave LDS, zero barriers.

__global__ __launch_bounds__(256) void sm_agg_kernel(
    const int* __restrict__ rowOff, const int* __restrict__ srcLst,
    const float* __restrict__ aSrcP, const float* __restrict__ aDstP,
    const unsigned short* __restrict__ H,
    const float* __restrict__ bias,
    const float* __restrict__ state, const float* __restrict__ wnsN,
    const float* __restrict__ bnsN, int addNext,
    unsigned short* __restrict__ Xout)
{
    __shared__ int   sSrcB[4 * 64];
    __shared__ float sAeB[4 * 4 * 64];   // [wave][batch][64]
    int tid = threadIdx.x;
    int w = tid >> 6, t = tid & 63;
    int n = blockIdx.x * 4 + w;
    int start = rowOff[n], end = rowOff[n + 1];
    int cnt = end - start;
    int*   sSrc = sSrcB + w * 64;
    float* sAe  = sAeB + w * 256;
    const uint4* H4 = (const uint4*)H;   // 16 uint4 per 128-bf16 row

    float adstb[4];
#pragma unroll
    for (int b = 0; b < 4; b++) adstb[b] = aDstP[b * N_NODES + n];

    if (cnt <= 64) {
        int sn = n;
        if (t < cnt) { sn = srcLst[start + t]; sSrc[t] = sn; }
        float ae0 = -1e30f, ae1 = -1e30f, ae2 = -1e30f, ae3 = -1e30f;
        {
            float v0 = aSrcP[0 * N_NODES + sn] + adstb[0];
            float v1 = aSrcP[1 * N_NODES + sn] + adstb[1];
            float v2 = aSrcP[2 * N_NODES + sn] + adstb[2];
            float v3 = aSrcP[3 * N_NODES + sn] + adstb[3];
            if (t < cnt) {
                ae0 = v0 > 0.f ? v0 : SLOPE * v0;
                ae1 = v1 > 0.f ? v1 : SLOPE * v1;
                ae2 = v2 > 0.f ? v2 : SLOPE * v2;
                ae3 = v3 > 0.f ? v3 : SLOPE * v3;
            }
        }
        float m0 = ae0, m1 = ae1, m2 = ae2, m3 = ae3;
#pragma unroll
        for (int off = 1; off < 64; off <<= 1) {
            m0 = fmaxf(m0, __shfl_xor(m0, off));
            m1 = fmaxf(m1, __shfl_xor(m1, off));
            m2 = fmaxf(m2, __shfl_xor(m2, off));
            m3 = fmaxf(m3, __shfl_xor(m3, off));
        }
        float e0 = (t < cnt) ? __expf(ae0 - m0) : 0.f;
        float e1 = (t < cnt) ? __expf(ae1 - m1) : 0.f;
        float e2 = (t < cnt) ? __expf(ae2 - m2) : 0.f;
        float e3 = (t < cnt) ? __expf(ae3 - m3) : 0.f;
        float s0 = e0, s1 = e1, s2 = e2, s3 = e3;
#pragma unroll
        for (int off = 1; off < 64; off <<= 1) {
            s0 += __shfl_xor(s0, off);
            s1 += __shfl_xor(s1, off);
            s2 += __shfl_xor(s2, off);
            s3 += __shfl_xor(s3, off);
        }
        if (t < cnt) {
            sAe[0 * 64 + t] = e0 / s0;
            sAe[1 * 64 + t] = e1 / s1;
            sAe[2 * 64 + t] = e2 / s2;
            sAe[3 * 64 + t] = e3 / s3;
        }
        int cntE = (cnt + 3) & ~3;
        if (t >= cnt && t < cntE) {
            sSrc[t] = n;
            sAe[0 * 64 + t] = 0.f; sAe[1 * 64 + t] = 0.f;
            sAe[2 * 64 + t] = 0.f; sAe[3 * 64 + t] = 0.f;
        }

        int esub = t >> 4, c16 = t & 15;
        float a[4][8];
#pragma unroll
        for (int b = 0; b < 4; b++)
#pragma unroll
            for (int k = 0; k < 8; k++) a[b][k] = 0.f;

        int j = 0;
        for (; j + 8 <= cntE; j += 8) {
            int j0 = j + esub, j1 = j + 4 + esub;
            int sn0 = sSrc[j0], sn1 = sSrc[j1];
            uint4 h0[4], h1[4]; float l0[4], l1[4];
#pragma unroll
            for (int b = 0; b < 4; b++) {
                h0[b] = H4[((size_t)(b * N_NODES + sn0)) * 16 + c16];
                h1[b] = H4[((size_t)(b * N_NODES + sn1)) * 16 + c16];
                l0[b] = sAe[b * 64 + j0];
                l1[b] = sAe[b * 64 + j1];
            }
#pragma unroll
            for (int b = 0; b < 4; b++) {
                a[b][0] += l0[b] * bflo(h0[b].x); a[b][1] += l0[b] * bfhi(h0[b].x);
                a[b][2] += l0[b] * bflo(h0[b].y); a[b][3] += l0[b] * bfhi(h0[b].y);
                a[b][4] += l0[b] * bflo(h0[b].z); a[b][5] += l0[b] * bfhi(h0[b].z);
                a[b][6] += l0[b] * bflo(h0[b].w); a[b][7] += l0[b] * bfhi(h0[b].w);
                a[b][0] += l1[b] * bflo(h1[b].x); a[b][1] += l1[b] * bfhi(h1[b].x);
                a[b][2] += l1[b] * bflo(h1[b].y); a[b][3] += l1[b] * bfhi(h1[b].y);
                a[b][4] += l1[b] * bflo(h1[b].z); a[b][5] += l1[b] * bfhi(h1[b].z);
                a[b][6] += l1[b] * bflo(h1[b].w); a[b][7] += l1[b] * bfhi(h1[b].w);
            }
        }
        for (; j < cntE; j += 4) {
            int jj = j + esub;
            int sn2 = sSrc[jj];
            uint4 h[4]; float al[4];
#pragma unroll
            for (int b = 0; b < 4; b++) {
                h[b] = H4[((size_t)(b * N_NODES + sn2)) * 16 + c16];
                al[b] = sAe[b * 64 + jj];
            }
#pragma unroll
            for (int b = 0; b < 4; b++) {
                a[b][0] += al[b] * bflo(h[b].x); a[b][1] += al[b] * bfhi(h[b].x);
                a[b][2] += al[b] * bflo(h[b].y); a[b][3] += al[b] * bfhi(h[b].y);
                a[b][4] += al[b] * bflo(h[b].z); a[b][5] += al[b] * bfhi(h[b].z);
                a[b][6] += al[b] * bflo(h[b].w); a[b][7] += al[b] * bfhi(h[b].w);
            }
        }
#pragma unroll
        for (int b = 0; b < 4; b++)
#pragma unroll
            for (int k = 0; k < 8; k++) {
                a[b][k] += __shfl_xor(a[b][k], 16);
                a[b][k] += __shfl_xor(a[b][k], 32);
            }
        if (esub == 0) {
            int d0 = c16 * 8;
#pragma unroll
            for (int b = 0; b < 4; b++) {
                float o[8];
#pragma unroll
                for (int k = 0; k < 8; k++) o[k] = fmaxf(a[b][k] + bias[d0 + k], 0.f);
                if (addNext) {
                    float st = state[b * N_NODES + n];
#pragma unroll
                    for (int k = 0; k < 8; k++) o[k] += st * wnsN[d0 + k] + bnsN[d0 + k];
                }
                uint4 u;
                u.x = (unsigned)f2bf(o[0]) | ((unsigned)f2bf(o[1]) << 16);
                u.y = (unsigned)f2bf(o[2]) | ((unsigned)f2bf(o[3]) << 16);
                u.z = (unsigned)f2bf(o[4]) | ((unsigned)f2bf(o[5]) << 16);
                u.w = (unsigned)f2bf(o[6]) | ((unsigned)f2bf(o[7]) << 16);
                ((uint4*)Xout)[((size_t)(b * N_NODES + n)) * 16 + c16] = u;
            }
        }
    } else {
        // fallback (deg > 64, rare) — serial over batches, per-wave LDS
        const unsigned* Hu = (const unsigned*)H;
#pragma unroll 1
        for (int bb = 0; bb < 4; bb++) {
            int gb = bb * N_NODES;
            float adst = adstb[bb];
            float m = -1e30f;
            for (int i = start + t; i < end; i += 64) {
                int sn = srcLst[i];
                float v = aSrcP[gb + sn] + adst;
                m = fmaxf(m, v > 0.f ? v : SLOPE * v);
            }
            m = fmaxf(m, __shfl_xor(m, 1));  m = fmaxf(m, __shfl_xor(m, 2));
            m = fmaxf(m, __shfl_xor(m, 4));  m = fmaxf(m, __shfl_xor(m, 8));
            m = fmaxf(m, __shfl_xor(m, 16)); m = fmaxf(m, __shfl_xor(m, 32));
            float s = 0.f;
            for (int i = start + t; i < end; i += 64) {
                int sn = srcLst[i];
                float v = aSrcP[gb + sn] + adst;
                float ae2 = v > 0.f ? v : SLOPE * v;
                s += __expf(ae2 - m);
            }
            s += __shfl_xor(s, 1);  s += __shfl_xor(s, 2);  s += __shfl_xor(s, 4);
            s += __shfl_xor(s, 8);  s += __shfl_xor(s, 16); s += __shfl_xor(s, 32);
            float inv = 1.f / s;
            float accx = 0.f, accy = 0.f;
            for (int c0 = start; c0 < end; c0 += 64) {
                int c = min(64, end - c0);
                if (t < c) {
                    int sn = srcLst[c0 + t];
                    sSrc[t] = sn;
                    float v = aSrcP[gb + sn] + adst;
                    float ae2 = v > 0.f ? v : SLOPE * v;
                    sAe[t] = __expf(ae2 - m);
                }
                for (int j = 0; j < c; j++) {
                    float a0 = sAe[j];
                    unsigned h0 = Hu[(size_t)(gb + sSrc[j]) * 64 + t];
                    accx += a0 * bflo(h0);
                    accy += a0 * bfhi(h0);
                }
            }
            float ox = fmaxf(accx * inv + bias[2 * t], 0.f);
            float oy = fmaxf(accy * inv + bias[2 * t + 1], 0.f);
            if (addNext) {
                float st = state[gb + n];
                ox += st * wnsN[2 * t]     + bnsN[2 * t];
                oy += st * wnsN[2 * t + 1] + bnsN[2 * t + 1];
            }
            ((unsigned*)Xout)[(size_t)(gb + n) * 64 + t] =
                (unsigned)f2bf(ox) | ((unsigned)f2bf(oy) << 16);
        }
    }
}

// ---------------- head ----------------

__global__ __launch_bounds__(128) void sum_nodes_kernel(const unsigned short* __restrict__ X, float* state_emb) {
    int cx = blockIdx.x, b = blockIdx.y, d = threadIdx.x;
    int n0 = cx * 157, n1 = n0 + 157;
    if (n1 > N_NODES) n1 = N_NODES;
    float acc = 0.f;
    for (int n = n0; n < n1; n++) acc += bf2f(X[(size_t)(b * N_NODES + n) * 128 + d]);
    atomicAdd(&state_emb[b * 128 + d], acc);
}

// ---------------- final: out = relu(X3@W2+b2).W3[128:] + c1[b] + b3 ; c1 inline ----------------

__global__ __launch_bounds__(256) void final_mfma(
    const unsigned short* __restrict__ X,
    const unsigned short* __restrict__ WThi, const unsigned short* __restrict__ WTlo,
    const float* __restrict__ b2, const float* __restrict__ W3,
    const float* __restrict__ b3,
    const float* __restrict__ state_emb, const float* __restrict__ W1,
    const float* __restrict__ b1,
    float* __restrict__ out)
{
    __shared__ float sB2[128], sW3[128];
    __shared__ float sPart[64 * 4];
    __shared__ float sC1p[8], sC1[4];

    int tid = threadIdx.x;
    int g0 = blockIdx.x * 64;
    int w = tid >> 6, lane = tid & 63;
    int quad = lane >> 4, mcol = lane & 15;

    if (tid < 128) { sB2[tid] = b2[tid]; sW3[tid] = W3[128 + tid]; }

    {
        int d = tid & 127;
        int bh = tid >> 7;   // half 0: b={0,2}; half 1: b={1,3}
        float p0 = b1[d], p1 = b1[d];
        for (int k = 0; k < 128; k++) {
            float wv = W1[k * 128 + d];
            p0 += state_emb[bh * 128 + k] * wv;
            p1 += state_emb[(bh + 2) * 128 + k] * wv;
        }
        float w3d = W3[d];
        p0 = fmaxf(p0, 0.f) * w3d;
        p1 = fmaxf(p1, 0.f) * w3d;
#pragma unroll
        for (int off = 1; off < 64; off <<= 1) {
            p0 += __shfl_xor(p0, off);
            p1 += __shfl_xor(p1, off);
        }
        if (lane == 0) { sC1p[w * 2 + 0] = p0; sC1p[w * 2 + 1] = p1; }
    }
    __syncthreads();
    if (tid == 0) {
        sC1[0] = sC1p[0] + sC1p[2];  sC1[2] = sC1p[1] + sC1p[3];
        sC1[1] = sC1p[4] + sC1p[6];  sC1[3] = sC1p[5] + sC1p[7];
    }

    float4v acc[4][2];
#pragma unroll
    for (int mt = 0; mt < 4; mt++)
#pragma unroll
        for (int nt = 0; nt < 2; nt++) acc[mt][nt] = (float4v){0.f, 0.f, 0.f, 0.f};

#pragma unroll 1
    for (int term = 0; term < 2; term++) {
        const unsigned short* WT = term ? WTlo : WThi;
        short8 Bf[4][2];
#pragma unroll
        for (int kc = 0; kc < 4; kc++)
#pragma unroll
            for (int nt = 0; nt < 2; nt++)
                Bf[kc][nt] = *(const short8*)(WT + (w * 32 + nt * 16 + mcol) * 128 + kc * 32 + quad * 8);
#pragma unroll
        for (int kc = 0; kc < 4; kc++) {
            short8 Aa[4];
#pragma unroll
            for (int mt = 0; mt < 4; mt++)
                Aa[mt] = *(const short8*)(X + (size_t)(g0 + mt * 16 + mcol) * 128 + kc * 32 + quad * 8);
#pragma unroll
            for (int mt = 0; mt < 4; mt++)
#pragma unroll
                for (int nt = 0; nt < 2; nt++)
                    acc[mt][nt] = __builtin_amdgcn_mfma_f32_16x16x32_bf16(Aa[mt], Bf[kc][nt], acc[mt][nt], 0, 0, 0);
        }
    }

    float pp[16];
#pragma unroll
    for (int r16 = 0; r16 < 16; r16++) pp[r16] = 0.f;
#pragma unroll
    for (int mt = 0; mt < 4; mt++)
#pragma unroll
        for (int nt = 0; nt < 2; nt++)
#pragma unroll
            for (int reg = 0; reg < 4; reg++) {
                int col = w * 32 + nt * 16 + mcol;
                float v = acc[mt][nt][reg] + sB2[col];
                v = v > 0.f ? v : 0.f;
                pp[mt * 4 + reg] += v * sW3[col];
            }
#pragma unroll
    for (int off = 1; off < 16; off <<= 1)
#pragma unroll
        for (int r16 = 0; r16 < 16; r16++)
            pp[r16] += __shfl_xor(pp[r16], off);
    if (mcol == 0) {
#pragma unroll
        for (int r16 = 0; r16 < 16; r16++) {
            int row = (r16 >> 2) * 16 + quad * 4 + (r16 & 3);
            sPart[row * 4 + w] = pp[r16];
        }
    }
    __syncthreads();
    if (tid < 64) {
        float p = sPart[tid * 4] + sPart[tid * 4 + 1] + sPart[tid * 4 + 2] + sPart[tid * 4 + 3];
        int g = g0 + tid;
        int b = g / N_NODES;
        out[g] = p + sC1[b] + b3[0];   // batch-major: out index == g
    }
}

// ---------------- launch ----------------

extern "C" void kernel_launch(void* const* d_in, const int* in_sizes, int n_in,
                              void* d_out, int out_size, void* d_ws, size_t ws_size,
                              hipStream_t stream) {
    const float* state    = (const float*)d_in[0];   // [B,N]
    const float* strucEmb = (const float*)d_in[1];   // [N,128]
    const int*   edge_idx = (const int*)d_in[2];     // [2,Etot]
    const float* gat_W    = (const float*)d_in[3];   // [3,128,128]
    const float* gat_aS   = (const float*)d_in[4];
    const float* gat_aD   = (const float*)d_in[5];
    const float* gat_Wns  = (const float*)d_in[6];
    const float* gat_bns  = (const float*)d_in[7];
    const float* gat_bias = (const float*)d_in[8];
    const float* W1 = (const float*)d_in[9];
    const float* b1 = (const float*)d_in[10];
    const float* W2 = (const float*)d_in[11];
    const float* b2 = (const float*)d_in[12];
    const float* W3 = (const float*)d_in[13];
    const float* b3 = (const float*)d_in[14];
    float* out = (float*)d_out;

    int Etot = in_sizes[2] / 2;
    const int* srcArr = edge_idx;
    const int* dstArr = edge_idx + Etot;

    float* ws = (float*)d_ws;
    unsigned short* Xb = (unsigned short*)ws;              // 5,120,000 us
    unsigned short* Hb = (unsigned short*)(ws + 2560000);  // 5,120,000 us
    float* aSrcP       = ws + 5120000;                     // 40,000 f
    float* aDstP       = ws + 5160000;                     // 40,000 f
    float* state_emb   = ws + 5200000;                     // 512 f
    unsigned short* whi = (unsigned short*)(ws + 5200516); // 65,536 us
    unsigned short* wlo = whi + 4 * 16384;                 // 65,536 us
    int*   iws         = (int*)(ws + 5200516 + 65536);
    int*   rowOff      = iws;                              // N+1
    int*   deg         = iws + 10001;
    int*   cursor      = deg + 10000;
    int*   srcLst      = cursor + 10000;                   // Etot

    setup_kernel<<<2796, 256, 0, stream>>>(strucEmb, state, gat_Wns, gat_bns,
                                           gat_W, W2, Xb, whi, wlo, deg, cursor, state_emb);
    hist_kernel<<<(Etot + 255) / 256, 256, 0, stream>>>(dstArr, Etot, deg);
    scan_kernel<<<1, 1024, 0, stream>>>(deg, rowOff);
    scatter_kernel<<<(Etot + 255) / 256, 256, 0, stream>>>(srcArr, dstArr, Etot, rowOff, cursor, srcLst);

    for (int l = 0; l < 3; l++) {
        gemm_att_mfma<<<BN / 64, 256, 0, stream>>>(
            Xb, whi + (size_t)l * 16384, wlo + (size_t)l * 16384,
            gat_aS + l * 128, gat_aD + l * 128, Hb, aSrcP, aDstP);
        sm_agg_kernel<<<N_NODES / 4, 256, 0, stream>>>(
            rowOff, srcLst, aSrcP, aDstP, Hb, gat_bias + l * 128,
            state, gat_Wns + (l + 1 < 3 ? (l + 1) * 128 : 0),
            gat_bns + (l + 1 < 3 ? (l + 1) * 128 : 0), (l < 2) ? 1 : 0, Xb);
    }

    sum_nodes_kernel<<<dim3(64, B_SZ), 128, 0, stream>>>(Xb, state_emb);
    final_mfma<<<BN / 64, 256, 0, stream>>>(Xb, whi + 3 * 16384, wlo + 3 * 16384,
                                            b2, W3, b3, state_emb, W1, b1, out);
}

// Round 8
// 333.293 us; speedup vs baseline: 1.0498x; 1.0498x over previous
//
#include <hip/hip_runtime.h>
#include <math.h>

#define N_NODES 10000
#define B_SZ 4
#define SLOPE 0.01f
#define BN (B_SZ * N_NODES)
#define PADK 136   // ushorts per LDS C-row (272B, 16B-aligned)

typedef __attribute__((ext_vector_type(8))) short short8;
typedef __attribute__((ext_vector_type(4))) float float4v;

__device__ __forceinline__ unsigned short f2bf(float f) {
    unsigned u = __builtin_bit_cast(unsigned, f);
    u += 0x7fffu + ((u >> 16) & 1u);   // RNE
    return (unsigned short)(u >> 16);
}
__device__ __forceinline__ float bf2f(unsigned short s) {
    unsigned u = ((unsigned)s) << 16;
    return __builtin_bit_cast(float, u);
}
__device__ __forceinline__ float bflo(unsigned u) { return __builtin_bit_cast(float, u << 16); }
__device__ __forceinline__ float bfhi(unsigned u) { return __builtin_bit_cast(float, u & 0xffff0000u); }

// All activations batch-major: row index g = b*N_NODES + n.

// ---------------- fused setup: prep0 (vectorized x8) + wconv + init ----------------

__global__ __launch_bounds__(256) void setup_kernel(
    const float* __restrict__ strucEmb, const float* __restrict__ state,
    const float* __restrict__ Wns0, const float* __restrict__ bns0,
    const float* __restrict__ gatW, const float* __restrict__ W2,
    unsigned short* __restrict__ XS,
    unsigned short* __restrict__ whi, unsigned short* __restrict__ wlo,
    int* deg, int* cursor, float* state_emb)
{
    int bx = blockIdx.x, tid = threadIdx.x;
    if (bx < 2500) {
        int base = (bx * 256 + tid) * 8;       // element index, 8 per thread, same row g
        int g = base >> 7, d0 = base & 127;
        int n = g - (g / N_NODES) * N_NODES;
        float st = state[g];
        const float* se = strucEmb + (size_t)n * 128 + d0;
        const float* wp = Wns0 + d0;
        const float* bp = bns0 + d0;
        short8 v;
#pragma unroll
        for (int j = 0; j < 8; j++)
            v[j] = (short)f2bf(se[j] + st * wp[j] + bp[j]);
        *(short8*)(XS + base) = v;
    } else if (bx < 2756) {
        int i = (bx - 2500) * 256 + tid;     // 0..65535
        int w = i >> 14, rem = i & 16383;
        int k = rem >> 7, c = rem & 127;
        const float* src = (w < 3) ? (gatW + (size_t)w * 16384) : W2;
        float v = src[k * 128 + c];
        unsigned short h = f2bf(v);
        whi[w * 16384 + c * 128 + k] = h;
        wlo[w * 16384 + c * 128 + k] = f2bf(v - bf2f(h));
    } else {
        int i = (bx - 2756) * 256 + tid;
        if (i < N_NODES) { deg[i] = 0; cursor[i] = 0; }
        if (i < 512) state_emb[i] = 0.f;
    }
}

// ---------------- CSR build ----------------

__global__ __launch_bounds__(256) void hist_kernel(const int* __restrict__ dst, int Etot, int* deg) {
    int e = blockIdx.x * 256 + threadIdx.x;
    if (e < Etot) atomicAdd(&deg[dst[e]], 1);
}

__global__ __launch_bounds__(1024) void scan_kernel(const int* __restrict__ deg, int* __restrict__ rowOff) {
    __shared__ int wsum[16];
    int tid = threadIdx.x;
    int lane = tid & 63, wid = tid >> 6;
    int base = tid * 10;
    int v[10]; int tot = 0;
#pragma unroll
    for (int j = 0; j < 10; j++) {
        int idx = base + j;
        int d = (idx < N_NODES) ? deg[idx] : 0;
        tot += d; v[j] = tot;
    }
    int incl = tot;
    for (int off = 1; off < 64; off <<= 1) {
        int t = __shfl_up(incl, off, 64);
        if (lane >= off) incl += t;
    }
    if (lane == 63) wsum[wid] = incl;
    __syncthreads();
    if (wid == 0) {
        int wv = (lane < 16) ? wsum[lane] : 0;
        for (int off = 1; off < 16; off <<= 1) {
            int t = __shfl_up(wv, off, 64);
            if (lane >= off) wv += t;
        }
        if (lane < 16) wsum[lane] = wv;
    }
    __syncthreads();
    int waveoff = (wid > 0) ? wsum[wid - 1] : 0;
    int excl = waveoff + incl - tot;
    if (tid == 0) rowOff[0] = 0;
#pragma unroll
    for (int j = 0; j < 10; j++) {
        int idx = base + j;
        if (idx < N_NODES) rowOff[idx + 1] = excl + v[j];
    }
}

__global__ __launch_bounds__(256) void scatter_kernel(const int* __restrict__ src, const int* __restrict__ dst,
                                                      int Etot, const int* __restrict__ rowOff,
                                                      int* cursor, int* __restrict__ srcLst) {
    int e = blockIdx.x * 256 + threadIdx.x;
    if (e < Etot) {
        int d = dst[e];
        int pos = rowOff[d] + atomicAdd(&cursor[d], 1);
        srcLst[pos] = src[e];
    }
}

// ---------------- MFMA GEMM (GAT layer): H(bf16) = XS(bf16) @ W ; att dots ----------------

__global__ __launch_bounds__(256) void gemm_att_mfma(
    const unsigned short* __restrict__ XS,
    const unsigned short* __restrict__ WThi, const unsigned short* __restrict__ WTlo,
    const float* __restrict__ attS, const float* __restrict__ attD,
    unsigned short* __restrict__ Hout, float* __restrict__ aSrcP, float* __restrict__ aDstP)
{
    __shared__ __align__(16) unsigned short sCus[64 * PADK];
    __shared__ float sAs[128], sAd[128];
    __shared__ float sPart[64 * 8];

    int tid = threadIdx.x;
    int g0 = blockIdx.x * 64;
    int w = tid >> 6, lane = tid & 63;
    int quad = lane >> 4, mcol = lane & 15;

    if (tid < 128) { sAs[tid] = attS[tid]; sAd[tid] = attD[tid]; }

    float4v acc[4][2];
#pragma unroll
    for (int mt = 0; mt < 4; mt++)
#pragma unroll
        for (int nt = 0; nt < 2; nt++) acc[mt][nt] = (float4v){0.f, 0.f, 0.f, 0.f};

#pragma unroll 1
    for (int term = 0; term < 2; term++) {
        const unsigned short* WT = term ? WTlo : WThi;
        short8 Bf[4][2];
#pragma unroll
        for (int kc = 0; kc < 4; kc++)
#pragma unroll
            for (int nt = 0; nt < 2; nt++)
                Bf[kc][nt] = *(const short8*)(WT + (w * 32 + nt * 16 + mcol) * 128 + kc * 32 + quad * 8);
#pragma unroll
        for (int kc = 0; kc < 4; kc++) {
            short8 Aa[4];
#pragma unroll
            for (int mt = 0; mt < 4; mt++)
                Aa[mt] = *(const short8*)(XS + (size_t)(g0 + mt * 16 + mcol) * 128 + kc * 32 + quad * 8);
#pragma unroll
            for (int mt = 0; mt < 4; mt++)
#pragma unroll
                for (int nt = 0; nt < 2; nt++)
                    acc[mt][nt] = __builtin_amdgcn_mfma_f32_16x16x32_bf16(Aa[mt], Bf[kc][nt], acc[mt][nt], 0, 0, 0);
        }
    }

    __syncthreads();   // sAs/sAd visible

    float pp[16], pd[16];
#pragma unroll
    for (int r16 = 0; r16 < 16; r16++) { pp[r16] = 0.f; pd[r16] = 0.f; }
#pragma unroll
    for (int mt = 0; mt < 4; mt++)
#pragma unroll
        for (int nt = 0; nt < 2; nt++)
#pragma unroll
            for (int reg = 0; reg < 4; reg++) {
                int row = mt * 16 + quad * 4 + reg;   // C/D: col=lane&15, row=quad*4+reg
                int col = w * 32 + nt * 16 + mcol;
                float v = acc[mt][nt][reg];
                sCus[row * PADK + col] = f2bf(v);
                pp[mt * 4 + reg] += v * sAs[col];
                pd[mt * 4 + reg] += v * sAd[col];
            }
#pragma unroll
    for (int off = 1; off < 16; off <<= 1)
#pragma unroll
        for (int r16 = 0; r16 < 16; r16++) {
            pp[r16] += __shfl_xor(pp[r16], off);
            pd[r16] += __shfl_xor(pd[r16], off);
        }
    if (mcol == 0) {
#pragma unroll
        for (int r16 = 0; r16 < 16; r16++) {
            int row = (r16 >> 2) * 16 + quad * 4 + (r16 & 3);
            sPart[row * 8 + w * 2 + 0] = pp[r16];
            sPart[row * 8 + w * 2 + 1] = pd[r16];
        }
    }
    __syncthreads();

    for (int i = tid; i < 64 * 16; i += 256) {
        int r = i >> 4, c8 = i & 15;
        uint4 u = *(uint4*)(sCus + r * PADK + c8 * 8);
        *(uint4*)(Hout + (size_t)(g0 + r) * 128 + c8 * 8) = u;
    }
    if (tid < 64) {
        float s0 = sPart[tid * 8] + sPart[tid * 8 + 2] + sPart[tid * 8 + 4] + sPart[tid * 8 + 6];
        float s1 = sPart[tid * 8 + 1] + sPart[tid * 8 + 3] + sPart[tid * 8 + 5] + sPart[tid * 8 + 7];
        aSrcP[g0 + tid] = s0;
        aDstP[g0 + tid] = s1;
    }
}

// ---------------- fused softmax + aggregate (+ next-layer Wns/bns), bf16 in/out ----------------
// Flat grid of 10000 blocks; (batch, node-chunk) derived from blockIdx.x so that under the
// round-robin block->XCD mapping each XCD pair serves ONE batch (L2 locality). Bijective.
// Gather: sSrc/sAe padded to all 64 slots (row n, alpha 0 -> loads valid, contribute 0);
// 8 independent uint4 loads issued per batch (edges 0..31), second batch only if cnt>32.
// One load-drain instead of 2-5 serialized ones (deg avg ~17 -> single batch).

__global__ __launch_bounds__(256) void sm_agg_kernel(
    const int* __restrict__ rowOff, const int* __restrict__ srcLst,
    const float* __restrict__ aSrcP, const float* __restrict__ aDstP,
    const unsigned short* __restrict__ H,
    const float* __restrict__ bias,
    const float* __restrict__ state, const float* __restrict__ wnsN,
    const float* __restrict__ bnsN, int addNext,
    unsigned short* __restrict__ Xout)
{
    __shared__ int   sSrcB[4 * 64];
    __shared__ float sAeB[4 * 64];
    int tid = threadIdx.x;
    int w = tid >> 6, t = tid & 63;
    int blk = blockIdx.x;
    int xcd = blk & 7;
    int b = xcd >> 1;
    int n = (((xcd & 1) * (N_NODES / 8) + (blk >> 3)) << 2) + w;
    int gb = b * N_NODES;
    int start = rowOff[n], end = rowOff[n + 1];
    int cnt = end - start;
    float adst = aDstP[gb + n];
    int*   sSrc = sSrcB + w * 64;
    float* sAe  = sAeB + w * 64;
    const uint4* H4 = (const uint4*)H;   // 16 uint4 per 128-bf16 row

    if (cnt <= 64) {
        float ae = -1e30f;
        if (t < cnt) {
            int sn = srcLst[start + t];
            sSrc[t] = sn;
            float v = aSrcP[gb + sn] + adst;
            ae = v > 0.f ? v : SLOPE * v;
        }
        float m = ae;
        m = fmaxf(m, __shfl_xor(m, 1));  m = fmaxf(m, __shfl_xor(m, 2));
        m = fmaxf(m, __shfl_xor(m, 4));  m = fmaxf(m, __shfl_xor(m, 8));
        m = fmaxf(m, __shfl_xor(m, 16)); m = fmaxf(m, __shfl_xor(m, 32));
        float e = (t < cnt) ? __expf(ae - m) : 0.f;
        float s = e;
        s += __shfl_xor(s, 1);  s += __shfl_xor(s, 2);  s += __shfl_xor(s, 4);
        s += __shfl_xor(s, 8);  s += __shfl_xor(s, 16); s += __shfl_xor(s, 32);
        float inv = 1.f / s;
        if (t < cnt) {
            sAe[t] = e * inv;
        } else {
            sSrc[t] = n;       // valid row, alpha 0
            sAe[t]  = 0.f;
        }

        int esub = t >> 4, c16 = t & 15;
        float a0 = 0.f, a1 = 0.f, a2 = 0.f, a3 = 0.f, a4 = 0.f, a5 = 0.f, a6 = 0.f, a7 = 0.f;

        {   // batch 1: edges 0..31 — 8 independent loads, one drain
            uint4 h[8]; float al[8];
#pragma unroll
            for (int r = 0; r < 8; r++) {
                int jj = r * 4 + esub;
                h[r]  = H4[(size_t)(gb + sSrc[jj]) * 16 + c16];
                al[r] = sAe[jj];
            }
#pragma unroll
            for (int r = 0; r < 8; r++) {
                a0 += al[r] * bflo(h[r].x); a1 += al[r] * bfhi(h[r].x);
                a2 += al[r] * bflo(h[r].y); a3 += al[r] * bfhi(h[r].y);
                a4 += al[r] * bflo(h[r].z); a5 += al[r] * bfhi(h[r].z);
                a6 += al[r] * bflo(h[r].w); a7 += al[r] * bfhi(h[r].w);
            }
        }
        if (cnt > 32) {   // batch 2: edges 32..63
            uint4 h[8]; float al[8];
#pragma unroll
            for (int r = 0; r < 8; r++) {
                int jj = 32 + r * 4 + esub;
                h[r]  = H4[(size_t)(gb + sSrc[jj]) * 16 + c16];
                al[r] = sAe[jj];
            }
#pragma unroll
            for (int r = 0; r < 8; r++) {
                a0 += al[r] * bflo(h[r].x); a1 += al[r] * bfhi(h[r].x);
                a2 += al[r] * bflo(h[r].y); a3 += al[r] * bfhi(h[r].y);
                a4 += al[r] * bflo(h[r].z); a5 += al[r] * bfhi(h[r].z);
                a6 += al[r] * bflo(h[r].w); a7 += al[r] * bfhi(h[r].w);
            }
        }

        a0 += __shfl_xor(a0, 16); a1 += __shfl_xor(a1, 16);
        a2 += __shfl_xor(a2, 16); a3 += __shfl_xor(a3, 16);
        a4 += __shfl_xor(a4, 16); a5 += __shfl_xor(a5, 16);
        a6 += __shfl_xor(a6, 16); a7 += __shfl_xor(a7, 16);
        a0 += __shfl_xor(a0, 32); a1 += __shfl_xor(a1, 32);
        a2 += __shfl_xor(a2, 32); a3 += __shfl_xor(a3, 32);
        a4 += __shfl_xor(a4, 32); a5 += __shfl_xor(a5, 32);
        a6 += __shfl_xor(a6, 32); a7 += __shfl_xor(a7, 32);
        if (esub == 0) {
            int d0 = c16 * 8;
            float o0 = fmaxf(a0 + bias[d0],     0.f);
            float o1 = fmaxf(a1 + bias[d0 + 1], 0.f);
            float o2 = fmaxf(a2 + bias[d0 + 2], 0.f);
            float o3 = fmaxf(a3 + bias[d0 + 3], 0.f);
            float o4 = fmaxf(a4 + bias[d0 + 4], 0.f);
            float o5 = fmaxf(a5 + bias[d0 + 5], 0.f);
            float o6 = fmaxf(a6 + bias[d0 + 6], 0.f);
            float o7 = fmaxf(a7 + bias[d0 + 7], 0.f);
            if (addNext) {
                float st = state[gb + n];
                o0 += st * wnsN[d0]     + bnsN[d0];
                o1 += st * wnsN[d0 + 1] + bnsN[d0 + 1];
                o2 += st * wnsN[d0 + 2] + bnsN[d0 + 2];
                o3 += st * wnsN[d0 + 3] + bnsN[d0 + 3];
                o4 += st * wnsN[d0 + 4] + bnsN[d0 + 4];
                o5 += st * wnsN[d0 + 5] + bnsN[d0 + 5];
                o6 += st * wnsN[d0 + 6] + bnsN[d0 + 6];
                o7 += st * wnsN[d0 + 7] + bnsN[d0 + 7];
            }
            uint4 u;
            u.x = (unsigned)f2bf(o0) | ((unsigned)f2bf(o1) << 16);
            u.y = (unsigned)f2bf(o2) | ((unsigned)f2bf(o3) << 16);
            u.z = (unsigned)f2bf(o4) | ((unsigned)f2bf(o5) << 16);
            u.w = (unsigned)f2bf(o6) | ((unsigned)f2bf(o7) << 16);
            ((uint4*)Xout)[(size_t)(gb + n) * 16 + c16] = u;
        }
    } else {
        // fallback (deg > 64, rare) — per-wave LDS, no barriers needed
        const unsigned* Hu = (const unsigned*)H;
        float m = -1e30f;
        for (int i = start + t; i < end; i += 64) {
            int sn = srcLst[i];
            float v = aSrcP[gb + sn] + adst;
            m = fmaxf(m, v > 0.f ? v : SLOPE * v);
        }
        m = fmaxf(m, __shfl_xor(m, 1));  m = fmaxf(m, __shfl_xor(m, 2));
        m = fmaxf(m, __shfl_xor(m, 4));  m = fmaxf(m, __shfl_xor(m, 8));
        m = fmaxf(m, __shfl_xor(m, 16)); m = fmaxf(m, __shfl_xor(m, 32));
        float s = 0.f;
        for (int i = start + t; i < end; i += 64) {
            int sn = srcLst[i];
            float v = aSrcP[gb + sn] + adst;
            float ae2 = v > 0.f ? v : SLOPE * v;
            s += __expf(ae2 - m);
        }
        s += __shfl_xor(s, 1);  s += __shfl_xor(s, 2);  s += __shfl_xor(s, 4);
        s += __shfl_xor(s, 8);  s += __shfl_xor(s, 16); s += __shfl_xor(s, 32);
        float inv = 1.f / s;
        float accx = 0.f, accy = 0.f;
        for (int c0 = start; c0 < end; c0 += 64) {
            int c = min(64, end - c0);
            if (t < c) {
                int sn = srcLst[c0 + t];
                sSrc[t] = sn;
                float v = aSrcP[gb + sn] + adst;
                float ae2 = v > 0.f ? v : SLOPE * v;
                sAe[t] = __expf(ae2 - m);
            }
            for (int j = 0; j < c; j++) {
                float a0 = sAe[j];
                unsigned h0 = Hu[(size_t)(gb + sSrc[j]) * 64 + t];
                accx += a0 * bflo(h0);
                accy += a0 * bfhi(h0);
            }
        }
        float ox = fmaxf(accx * inv + bias[2 * t], 0.f);
        float oy = fmaxf(accy * inv + bias[2 * t + 1], 0.f);
        if (addNext) {
            float st = state[gb + n];
            ox += st * wnsN[2 * t]     + bnsN[2 * t];
            oy += st * wnsN[2 * t + 1] + bnsN[2 * t + 1];
        }
        ((unsigned*)Xout)[(size_t)(gb + n) * 64 + t] =
            (unsigned)f2bf(ox) | ((unsigned)f2bf(oy) << 16);
    }
}

// ---------------- head ----------------

__global__ __launch_bounds__(128) void sum_nodes_kernel(const unsigned short* __restrict__ X, float* state_emb) {
    int cx = blockIdx.x, b = blockIdx.y, d = threadIdx.x;
    int n0 = cx * 157, n1 = n0 + 157;
    if (n1 > N_NODES) n1 = N_NODES;
    float acc = 0.f;
    for (int n = n0; n < n1; n++) acc += bf2f(X[(size_t)(b * N_NODES + n) * 128 + d]);
    atomicAdd(&state_emb[b * 128 + d], acc);
}

// ---------------- final: out = relu(X3@W2+b2).W3[128:] + c1[b] + b3 ; c1 inline ----------------

__global__ __launch_bounds__(256) void final_mfma(
    const unsigned short* __restrict__ X,
    const unsigned short* __restrict__ WThi, const unsigned short* __restrict__ WTlo,
    const float* __restrict__ b2, const float* __restrict__ W3,
    const float* __restrict__ b3,
    const float* __restrict__ state_emb, const float* __restrict__ W1,
    const float* __restrict__ b1,
    float* __restrict__ out)
{
    __shared__ float sB2[128], sW3[128];
    __shared__ float sPart[64 * 4];
    __shared__ float sC1p[8], sC1[4];

    int tid = threadIdx.x;
    int g0 = blockIdx.x * 64;
    int w = tid >> 6, lane = tid & 63;
    int quad = lane >> 4, mcol = lane & 15;

    if (tid < 128) { sB2[tid] = b2[tid]; sW3[tid] = W3[128 + tid]; }

    {
        int d = tid & 127;
        int bh = tid >> 7;   // half 0: b={0,2}; half 1: b={1,3}
        float p0 = b1[d], p1 = b1[d];
        for (int k = 0; k < 128; k++) {
            float wv = W1[k * 128 + d];
            p0 += state_emb[bh * 128 + k] * wv;
            p1 += state_emb[(bh + 2) * 128 + k] * wv;
        }
        float w3d = W3[d];
        p0 = fmaxf(p0, 0.f) * w3d;
        p1 = fmaxf(p1, 0.f) * w3d;
#pragma unroll
        for (int off = 1; off < 64; off <<= 1) {
            p0 += __shfl_xor(p0, off);
            p1 += __shfl_xor(p1, off);
        }
        if (lane == 0) { sC1p[w * 2 + 0] = p0; sC1p[w * 2 + 1] = p1; }
    }
    __syncthreads();
    if (tid == 0) {
        sC1[0] = sC1p[0] + sC1p[2];  sC1[2] = sC1p[1] + sC1p[3];
        sC1[1] = sC1p[4] + sC1p[6];  sC1[3] = sC1p[5] + sC1p[7];
    }

    float4v acc[4][2];
#pragma unroll
    for (int mt = 0; mt < 4; mt++)
#pragma unroll
        for (int nt = 0; nt < 2; nt++) acc[mt][nt] = (float4v){0.f, 0.f, 0.f, 0.f};

#pragma unroll 1
    for (int term = 0; term < 2; term++) {
        const unsigned short* WT = term ? WTlo : WThi;
        short8 Bf[4][2];
#pragma unroll
        for (int kc = 0; kc < 4; kc++)
#pragma unroll
            for (int nt = 0; nt < 2; nt++)
                Bf[kc][nt] = *(const short8*)(WT + (w * 32 + nt * 16 + mcol) * 128 + kc * 32 + quad * 8);
#pragma unroll
        for (int kc = 0; kc < 4; kc++) {
            short8 Aa[4];
#pragma unroll
            for (int mt = 0; mt < 4; mt++)
                Aa[mt] = *(const short8*)(X + (size_t)(g0 + mt * 16 + mcol) * 128 + kc * 32 + quad * 8);
#pragma unroll
            for (int mt = 0; mt < 4; mt++)
#pragma unroll
                for (int nt = 0; nt < 2; nt++)
                    acc[mt][nt] = __builtin_amdgcn_mfma_f32_16x16x32_bf16(Aa[mt], Bf[kc][nt], acc[mt][nt], 0, 0, 0);
        }
    }

    float pp[16];
#pragma unroll
    for (int r16 = 0; r16 < 16; r16++) pp[r16] = 0.f;
#pragma unroll
    for (int mt = 0; mt < 4; mt++)
#pragma unroll
        for (int nt = 0; nt < 2; nt++)
#pragma unroll
            for (int reg = 0; reg < 4; reg++) {
                int col = w * 32 + nt * 16 + mcol;
                float v = acc[mt][nt][reg] + sB2[col];
                v = v > 0.f ? v : 0.f;
                pp[mt * 4 + reg] += v * sW3[col];
            }
#pragma unroll
    for (int off = 1; off < 16; off <<= 1)
#pragma unroll
        for (int r16 = 0; r16 < 16; r16++)
            pp[r16] += __shfl_xor(pp[r16], off);
    if (mcol == 0) {
#pragma unroll
        for (int r16 = 0; r16 < 16; r16++) {
            int row = (r16 >> 2) * 16 + quad * 4 + (r16 & 3);
            sPart[row * 4 + w] = pp[r16];
        }
    }
    __syncthreads();
    if (tid < 64) {
        float p = sPart[tid * 4] + sPart[tid * 4 + 1] + sPart[tid * 4 + 2] + sPart[tid * 4 + 3];
        int g = g0 + tid;
        int b = g / N_NODES;
        out[g] = p + sC1[b] + b3[0];   // batch-major: out index == g
    }
}

// ---------------- launch ----------------

extern "C" void kernel_launch(void* const* d_in, const int* in_sizes, int n_in,
                              void* d_out, int out_size, void* d_ws, size_t ws_size,
                              hipStream_t stream) {
    const float* state    = (const float*)d_in[0];   // [B,N]
    const float* strucEmb = (const float*)d_in[1];   // [N,128]
    const int*   edge_idx = (const int*)d_in[2];     // [2,Etot]
    const float* gat_W    = (const float*)d_in[3];   // [3,128,128]
    const float* gat_aS   = (const float*)d_in[4];
    const float* gat_aD   = (const float*)d_in[5];
    const float* gat_Wns  = (const float*)d_in[6];
    const float* gat_bns  = (const float*)d_in[7];
    const float* gat_bias = (const float*)d_in[8];
    const float* W1 = (const float*)d_in[9];
    const float* b1 = (const float*)d_in[10];
    const float* W2 = (const float*)d_in[11];
    const float* b2 = (const float*)d_in[12];
    const float* W3 = (const float*)d_in[13];
    const float* b3 = (const float*)d_in[14];
    float* out = (float*)d_out;

    int Etot = in_sizes[2] / 2;
    const int* srcArr = edge_idx;
    const int* dstArr = edge_idx + Etot;

    float* ws = (float*)d_ws;
    unsigned short* Xb = (unsigned short*)ws;              // 5,120,000 us
    unsigned short* Hb = (unsigned short*)(ws + 2560000);  // 5,120,000 us
    float* aSrcP       = ws + 5120000;                     // 40,000 f
    float* aDstP       = ws + 5160000;                     // 40,000 f
    float* state_emb   = ws + 5200000;                     // 512 f
    unsigned short* whi = (unsigned short*)(ws + 5200516); // 65,536 us
    unsigned short* wlo = whi + 4 * 16384;                 // 65,536 us
    int*   iws         = (int*)(ws + 5200516 + 65536);
    int*   rowOff      = iws;                              // N+1
    int*   deg         = iws + 10001;
    int*   cursor      = deg + 10000;
    int*   srcLst      = cursor + 10000;                   // Etot

    setup_kernel<<<2796, 256, 0, stream>>>(strucEmb, state, gat_Wns, gat_bns,
                                           gat_W, W2, Xb, whi, wlo, deg, cursor, state_emb);
    hist_kernel<<<(Etot + 255) / 256, 256, 0, stream>>>(dstArr, Etot, deg);
    scan_kernel<<<1, 1024, 0, stream>>>(deg, rowOff);
    scatter_kernel<<<(Etot + 255) / 256, 256, 0, stream>>>(srcArr, dstArr, Etot, rowOff, cursor, srcLst);

    for (int l = 0; l < 3; l++) {
        gemm_att_mfma<<<BN / 64, 256, 0, stream>>>(
            Xb, whi + (size_t)l * 16384, wlo + (size_t)l * 16384,
            gat_aS + l * 128, gat_aD + l * 128, Hb, aSrcP, aDstP);
        sm_agg_kernel<<<N_NODES, 256, 0, stream>>>(
            rowOff, srcLst, aSrcP, aDstP, Hb, gat_bias + l * 128,
            state, gat_Wns + (l + 1 < 3 ? (l + 1) * 128 : 0),
            gat_bns + (l + 1 < 3 ? (l + 1) * 128 : 0), (l < 2) ? 1 : 0, Xb);
    }

    sum_nodes_kernel<<<dim3(64, B_SZ), 128, 0, stream>>>(Xb, state_emb);
    final_mfma<<<BN / 64, 256, 0, stream>>>(Xb, whi + 3 * 16384, wlo + 3 * 16384,
                                            b2, W3, b3, state_emb, W1, b1, out);
}

// Round 9
// 319.836 us; speedup vs baseline: 1.0939x; 1.0421x over previous
//
#include <hip/hip_runtime.h>
#include <math.h>

#define N_NODES 10000
#define B_SZ 4
#define SLOPE 0.01f
#define BN (B_SZ * N_NODES)
#define PADK 136   // ushorts per LDS C-row (272B, 16B-aligned)

typedef __attribute__((ext_vector_type(8))) short short8;
typedef __attribute__((ext_vector_type(4))) float float4v;

__device__ __forceinline__ unsigned short f2bf(float f) {
    unsigned u = __builtin_bit_cast(unsigned, f);
    u += 0x7fffu + ((u >> 16) & 1u);   // RNE
    return (unsigned short)(u >> 16);
}
__device__ __forceinline__ float bf2f(unsigned short s) {
    unsigned u = ((unsigned)s) << 16;
    return __builtin_bit_cast(float, u);
}
__device__ __forceinline__ float bflo(unsigned u) { return __builtin_bit_cast(float, u << 16); }
__device__ __forceinline__ float bfhi(unsigned u) { return __builtin_bit_cast(float, u & 0xffff0000u); }

// All activations batch-major: row index g = b*N_NODES + n.

// ---------------- fused setup: prep0 (vectorized x8) + wconv + init ----------------

__global__ __launch_bounds__(256) void setup_kernel(
    const float* __restrict__ strucEmb, const float* __restrict__ state,
    const float* __restrict__ Wns0, const float* __restrict__ bns0,
    const float* __restrict__ gatW, const float* __restrict__ W2,
    unsigned short* __restrict__ XS,
    unsigned short* __restrict__ whi, unsigned short* __restrict__ wlo,
    int* deg, int* cursor, float* state_emb)
{
    int bx = blockIdx.x, tid = threadIdx.x;
    if (bx < 2500) {
        int base = (bx * 256 + tid) * 8;       // element index, 8 per thread, same row g
        int g = base >> 7, d0 = base & 127;
        int n = g - (g / N_NODES) * N_NODES;
        float st = state[g];
        const float* se = strucEmb + (size_t)n * 128 + d0;
        const float* wp = Wns0 + d0;
        const float* bp = bns0 + d0;
        short8 v;
#pragma unroll
        for (int j = 0; j < 8; j++)
            v[j] = (short)f2bf(se[j] + st * wp[j] + bp[j]);
        *(short8*)(XS + base) = v;
    } else if (bx < 2756) {
        int i = (bx - 2500) * 256 + tid;     // 0..65535
        int w = i >> 14, rem = i & 16383;
        int k = rem >> 7, c = rem & 127;
        const float* src = (w < 3) ? (gatW + (size_t)w * 16384) : W2;
        float v = src[k * 128 + c];
        unsigned short h = f2bf(v);
        whi[w * 16384 + c * 128 + k] = h;
        wlo[w * 16384 + c * 128 + k] = f2bf(v - bf2f(h));
    } else {
        int i = (bx - 2756) * 256 + tid;
        if (i < N_NODES) { deg[i] = 0; cursor[i] = 0; }
        if (i < 512) state_emb[i] = 0.f;
    }
}

// ---------------- CSR build ----------------

__global__ __launch_bounds__(256) void hist_kernel(const int* __restrict__ dst, int Etot, int* deg) {
    int e = blockIdx.x * 256 + threadIdx.x;
    if (e < Etot) atomicAdd(&deg[dst[e]], 1);
}

__global__ __launch_bounds__(1024) void scan_kernel(const int* __restrict__ deg, int* __restrict__ rowOff) {
    __shared__ int wsum[16];
    int tid = threadIdx.x;
    int lane = tid & 63, wid = tid >> 6;
    int base = tid * 10;
    int v[10]; int tot = 0;
#pragma unroll
    for (int j = 0; j < 10; j++) {
        int idx = base + j;
        int d = (idx < N_NODES) ? deg[idx] : 0;
        tot += d; v[j] = tot;
    }
    int incl = tot;
    for (int off = 1; off < 64; off <<= 1) {
        int t = __shfl_up(incl, off, 64);
        if (lane >= off) incl += t;
    }
    if (lane == 63) wsum[wid] = incl;
    __syncthreads();
    if (wid == 0) {
        int wv = (lane < 16) ? wsum[lane] : 0;
        for (int off = 1; off < 16; off <<= 1) {
            int t = __shfl_up(wv, off, 64);
            if (lane >= off) wv += t;
        }
        if (lane < 16) wsum[lane] = wv;
    }
    __syncthreads();
    int waveoff = (wid > 0) ? wsum[wid - 1] : 0;
    int excl = waveoff + incl - tot;
    if (tid == 0) rowOff[0] = 0;
#pragma unroll
    for (int j = 0; j < 10; j++) {
        int idx = base + j;
        if (idx < N_NODES) rowOff[idx + 1] = excl + v[j];
    }
}

__global__ __launch_bounds__(256) void scatter_kernel(const int* __restrict__ src, const int* __restrict__ dst,
                                                      int Etot, const int* __restrict__ rowOff,
                                                      int* cursor, int* __restrict__ srcLst) {
    int e = blockIdx.x * 256 + threadIdx.x;
    if (e < Etot) {
        int d = dst[e];
        int pos = rowOff[d] + atomicAdd(&cursor[d], 1);
        srcLst[pos] = src[e];
    }
}

// ---------------- MFMA GEMM (GAT layer): H(bf16) = XS(bf16) @ W ; att dots ----------------

__global__ __launch_bounds__(256) void gemm_att_mfma(
    const unsigned short* __restrict__ XS,
    const unsigned short* __restrict__ WThi, const unsigned short* __restrict__ WTlo,
    const float* __restrict__ attS, const float* __restrict__ attD,
    unsigned short* __restrict__ Hout, float* __restrict__ aSrcP, float* __restrict__ aDstP)
{
    __shared__ __align__(16) unsigned short sCus[64 * PADK];
    __shared__ float sAs[128], sAd[128];
    __shared__ float sPart[64 * 8];

    int tid = threadIdx.x;
    int g0 = blockIdx.x * 64;
    int w = tid >> 6, lane = tid & 63;
    int quad = lane >> 4, mcol = lane & 15;

    if (tid < 128) { sAs[tid] = attS[tid]; sAd[tid] = attD[tid]; }

    float4v acc[4][2];
#pragma unroll
    for (int mt = 0; mt < 4; mt++)
#pragma unroll
        for (int nt = 0; nt < 2; nt++) acc[mt][nt] = (float4v){0.f, 0.f, 0.f, 0.f};

#pragma unroll 1
    for (int term = 0; term < 2; term++) {
        const unsigned short* WT = term ? WTlo : WThi;
        short8 Bf[4][2];
#pragma unroll
        for (int kc = 0; kc < 4; kc++)
#pragma unroll
            for (int nt = 0; nt < 2; nt++)
                Bf[kc][nt] = *(const short8*)(WT + (w * 32 + nt * 16 + mcol) * 128 + kc * 32 + quad * 8);
#pragma unroll
        for (int kc = 0; kc < 4; kc++) {
            short8 Aa[4];
#pragma unroll
            for (int mt = 0; mt < 4; mt++)
                Aa[mt] = *(const short8*)(XS + (size_t)(g0 + mt * 16 + mcol) * 128 + kc * 32 + quad * 8);
#pragma unroll
            for (int mt = 0; mt < 4; mt++)
#pragma unroll
                for (int nt = 0; nt < 2; nt++)
                    acc[mt][nt] = __builtin_amdgcn_mfma_f32_16x16x32_bf16(Aa[mt], Bf[kc][nt], acc[mt][nt], 0, 0, 0);
        }
    }

    __syncthreads();   // sAs/sAd visible

    float pp[16], pd[16];
#pragma unroll
    for (int r16 = 0; r16 < 16; r16++) { pp[r16] = 0.f; pd[r16] = 0.f; }
#pragma unroll
    for (int mt = 0; mt < 4; mt++)
#pragma unroll
        for (int nt = 0; nt < 2; nt++)
#pragma unroll
            for (int reg = 0; reg < 4; reg++) {
                int row = mt * 16 + quad * 4 + reg;   // C/D: col=lane&15, row=quad*4+reg
                int col = w * 32 + nt * 16 + mcol;
                float v = acc[mt][nt][reg];
                sCus[row * PADK + col] = f2bf(v);
                pp[mt * 4 + reg] += v * sAs[col];
                pd[mt * 4 + reg] += v * sAd[col];
            }
#pragma unroll
    for (int off = 1; off < 16; off <<= 1)
#pragma unroll
        for (int r16 = 0; r16 < 16; r16++) {
            pp[r16] += __shfl_xor(pp[r16], off);
            pd[r16] += __shfl_xor(pd[r16], off);
        }
    if (mcol == 0) {
#pragma unroll
        for (int r16 = 0; r16 < 16; r16++) {
            int row = (r16 >> 2) * 16 + quad * 4 + (r16 & 3);
            sPart[row * 8 + w * 2 + 0] = pp[r16];
            sPart[row * 8 + w * 2 + 1] = pd[r16];
        }
    }
    __syncthreads();

    for (int i = tid; i < 64 * 16; i += 256) {
        int r = i >> 4, c8 = i & 15;
        uint4 u = *(uint4*)(sCus + r * PADK + c8 * 8);
        *(uint4*)(Hout + (size_t)(g0 + r) * 128 + c8 * 8) = u;
    }
    if (tid < 64) {
        float s0 = sPart[tid * 8] + sPart[tid * 8 + 2] + sPart[tid * 8 + 4] + sPart[tid * 8 + 6];
        float s1 = sPart[tid * 8 + 1] + sPart[tid * 8 + 3] + sPart[tid * 8 + 5] + sPart[tid * 8 + 7];
        aSrcP[g0 + tid] = s0;
        aDstP[g0 + tid] = s1;
    }
}

// ---------------- fused softmax + aggregate (+ next-layer Wns/bns), bf16 in/out ----------------
// Flat grid of 10000 blocks; (batch, node-chunk) from blockIdx.x for XCD L2 locality (bijective).
// Gather: LDS slots padded to 80/wave (pad rows = self row n, alpha 0 -> valid cached loads).
// Batches of 5 independent uint4 loads = 20 edges per drain (mean deg ~17 -> 1 drain for ~80%
// of nodes). al read from LDS at consume time; VGPR stays <=64 -> full 8 waves/SIMD.

__global__ __launch_bounds__(256) void sm_agg_kernel(
    const int* __restrict__ rowOff, const int* __restrict__ srcLst,
    const float* __restrict__ aSrcP, const float* __restrict__ aDstP,
    const unsigned short* __restrict__ H,
    const float* __restrict__ bias,
    const float* __restrict__ state, const float* __restrict__ wnsN,
    const float* __restrict__ bnsN, int addNext,
    unsigned short* __restrict__ Xout)
{
    __shared__ int   sSrcB[4 * 80];
    __shared__ float sAeB[4 * 80];
    int tid = threadIdx.x;
    int w = tid >> 6, t = tid & 63;
    int blk = blockIdx.x;
    int xcd = blk & 7;
    int b = xcd >> 1;
    int n = (((xcd & 1) * (N_NODES / 8) + (blk >> 3)) << 2) + w;
    int gb = b * N_NODES;
    int start = rowOff[n], end = rowOff[n + 1];
    int cnt = end - start;
    float adst = aDstP[gb + n];
    int*   sSrc = sSrcB + w * 80;
    float* sAe  = sAeB + w * 80;
    const uint4* H4 = (const uint4*)H;   // 16 uint4 per 128-bf16 row

    if (cnt <= 64) {
        float ae = -1e30f;
        if (t < cnt) {
            int sn = srcLst[start + t];
            sSrc[t] = sn;
            float v = aSrcP[gb + sn] + adst;
            ae = v > 0.f ? v : SLOPE * v;
        }
        float m = ae;
        m = fmaxf(m, __shfl_xor(m, 1));  m = fmaxf(m, __shfl_xor(m, 2));
        m = fmaxf(m, __shfl_xor(m, 4));  m = fmaxf(m, __shfl_xor(m, 8));
        m = fmaxf(m, __shfl_xor(m, 16)); m = fmaxf(m, __shfl_xor(m, 32));
        float e = (t < cnt) ? __expf(ae - m) : 0.f;
        float s = e;
        s += __shfl_xor(s, 1);  s += __shfl_xor(s, 2);  s += __shfl_xor(s, 4);
        s += __shfl_xor(s, 8);  s += __shfl_xor(s, 16); s += __shfl_xor(s, 32);
        float inv = 1.f / s;
        if (t < cnt) {
            sAe[t] = e * inv;
        } else {
            sSrc[t] = n;       // valid row, alpha 0
            sAe[t]  = 0.f;
        }
        if (t < 16) {          // pad slots 64..79
            sSrc[64 + t] = n;
            sAe[64 + t]  = 0.f;
        }

        int esub = t >> 4, c16 = t & 15;
        float a0 = 0.f, a1 = 0.f, a2 = 0.f, a3 = 0.f, a4 = 0.f, a5 = 0.f, a6 = 0.f, a7 = 0.f;

        int nb = (cnt + 19) / 20;   // 1..4 batches of 20 edges (5 loads each)
#pragma unroll 1
        for (int bb = 0; bb < nb; bb++) {
            int j = bb * 20;
            int j0 = j + esub, j1 = j + 4 + esub, j2 = j + 8 + esub,
                j3 = j + 12 + esub, j4 = j + 16 + esub;
            uint4 h0 = H4[(size_t)(gb + sSrc[j0]) * 16 + c16];
            uint4 h1 = H4[(size_t)(gb + sSrc[j1]) * 16 + c16];
            uint4 h2 = H4[(size_t)(gb + sSrc[j2]) * 16 + c16];
            uint4 h3 = H4[(size_t)(gb + sSrc[j3]) * 16 + c16];
            uint4 h4 = H4[(size_t)(gb + sSrc[j4]) * 16 + c16];
            float l0 = sAe[j0], l1 = sAe[j1], l2 = sAe[j2], l3 = sAe[j3], l4 = sAe[j4];
            a0 += l0 * bflo(h0.x); a1 += l0 * bfhi(h0.x);
            a2 += l0 * bflo(h0.y); a3 += l0 * bfhi(h0.y);
            a4 += l0 * bflo(h0.z); a5 += l0 * bfhi(h0.z);
            a6 += l0 * bflo(h0.w); a7 += l0 * bfhi(h0.w);
            a0 += l1 * bflo(h1.x); a1 += l1 * bfhi(h1.x);
            a2 += l1 * bflo(h1.y); a3 += l1 * bfhi(h1.y);
            a4 += l1 * bflo(h1.z); a5 += l1 * bfhi(h1.z);
            a6 += l1 * bflo(h1.w); a7 += l1 * bfhi(h1.w);
            a0 += l2 * bflo(h2.x); a1 += l2 * bfhi(h2.x);
            a2 += l2 * bflo(h2.y); a3 += l2 * bfhi(h2.y);
            a4 += l2 * bflo(h2.z); a5 += l2 * bfhi(h2.z);
            a6 += l2 * bflo(h2.w); a7 += l2 * bfhi(h2.w);
            a0 += l3 * bflo(h3.x); a1 += l3 * bfhi(h3.x);
            a2 += l3 * bflo(h3.y); a3 += l3 * bfhi(h3.y);
            a4 += l3 * bflo(h3.z); a5 += l3 * bfhi(h3.z);
            a6 += l3 * bflo(h3.w); a7 += l3 * bfhi(h3.w);
            a0 += l4 * bflo(h4.x); a1 += l4 * bfhi(h4.x);
            a2 += l4 * bflo(h4.y); a3 += l4 * bfhi(h4.y);
            a4 += l4 * bflo(h4.z); a5 += l4 * bfhi(h4.z);
            a6 += l4 * bflo(h4.w); a7 += l4 * bfhi(h4.w);
        }

        a0 += __shfl_xor(a0, 16); a1 += __shfl_xor(a1, 16);
        a2 += __shfl_xor(a2, 16); a3 += __shfl_xor(a3, 16);
        a4 += __shfl_xor(a4, 16); a5 += __shfl_xor(a5, 16);
        a6 += __shfl_xor(a6, 16); a7 += __shfl_xor(a7, 16);
        a0 += __shfl_xor(a0, 32); a1 += __shfl_xor(a1, 32);
        a2 += __shfl_xor(a2, 32); a3 += __shfl_xor(a3, 32);
        a4 += __shfl_xor(a4, 32); a5 += __shfl_xor(a5, 32);
        a6 += __shfl_xor(a6, 32); a7 += __shfl_xor(a7, 32);
        if (esub == 0) {
            int d0 = c16 * 8;
            float o0 = fmaxf(a0 + bias[d0],     0.f);
            float o1 = fmaxf(a1 + bias[d0 + 1], 0.f);
            float o2 = fmaxf(a2 + bias[d0 + 2], 0.f);
            float o3 = fmaxf(a3 + bias[d0 + 3], 0.f);
            float o4 = fmaxf(a4 + bias[d0 + 4], 0.f);
            float o5 = fmaxf(a5 + bias[d0 + 5], 0.f);
            float o6 = fmaxf(a6 + bias[d0 + 6], 0.f);
            float o7 = fmaxf(a7 + bias[d0 + 7], 0.f);
            if (addNext) {
                float st = state[gb + n];
                o0 += st * wnsN[d0]     + bnsN[d0];
                o1 += st * wnsN[d0 + 1] + bnsN[d0 + 1];
                o2 += st * wnsN[d0 + 2] + bnsN[d0 + 2];
                o3 += st * wnsN[d0 + 3] + bnsN[d0 + 3];
                o4 += st * wnsN[d0 + 4] + bnsN[d0 + 4];
                o5 += st * wnsN[d0 + 5] + bnsN[d0 + 5];
                o6 += st * wnsN[d0 + 6] + bnsN[d0 + 6];
                o7 += st * wnsN[d0 + 7] + bnsN[d0 + 7];
            }
            uint4 u;
            u.x = (unsigned)f2bf(o0) | ((unsigned)f2bf(o1) << 16);
            u.y = (unsigned)f2bf(o2) | ((unsigned)f2bf(o3) << 16);
            u.z = (unsigned)f2bf(o4) | ((unsigned)f2bf(o5) << 16);
            u.w = (unsigned)f2bf(o6) | ((unsigned)f2bf(o7) << 16);
            ((uint4*)Xout)[(size_t)(gb + n) * 16 + c16] = u;
        }
    } else {
        // fallback (deg > 64, rare) — per-wave LDS, no barriers needed
        const unsigned* Hu = (const unsigned*)H;
        float m = -1e30f;
        for (int i = start + t; i < end; i += 64) {
            int sn = srcLst[i];
            float v = aSrcP[gb + sn] + adst;
            m = fmaxf(m, v > 0.f ? v : SLOPE * v);
        }
        m = fmaxf(m, __shfl_xor(m, 1));  m = fmaxf(m, __shfl_xor(m, 2));
        m = fmaxf(m, __shfl_xor(m, 4));  m = fmaxf(m, __shfl_xor(m, 8));
        m = fmaxf(m, __shfl_xor(m, 16)); m = fmaxf(m, __shfl_xor(m, 32));
        float s = 0.f;
        for (int i = start + t; i < end; i += 64) {
            int sn = srcLst[i];
            float v = aSrcP[gb + sn] + adst;
            float ae2 = v > 0.f ? v : SLOPE * v;
            s += __expf(ae2 - m);
        }
        s += __shfl_xor(s, 1);  s += __shfl_xor(s, 2);  s += __shfl_xor(s, 4);
        s += __shfl_xor(s, 8);  s += __shfl_xor(s, 16); s += __shfl_xor(s, 32);
        float inv = 1.f / s;
        float accx = 0.f, accy = 0.f;
        for (int c0 = start; c0 < end; c0 += 64) {
            int c = min(64, end - c0);
            if (t < c) {
                int sn = srcLst[c0 + t];
                sSrc[t] = sn;
                float v = aSrcP[gb + sn] + adst;
                float ae2 = v > 0.f ? v : SLOPE * v;
                sAe[t] = __expf(ae2 - m);
            }
            for (int j = 0; j < c; j++) {
                float a0 = sAe[j];
                unsigned h0 = Hu[(size_t)(gb + sSrc[j]) * 64 + t];
                accx += a0 * bflo(h0);
                accy += a0 * bfhi(h0);
            }
        }
        float ox = fmaxf(accx * inv + bias[2 * t], 0.f);
        float oy = fmaxf(accy * inv + bias[2 * t + 1], 0.f);
        if (addNext) {
            float st = state[gb + n];
            ox += st * wnsN[2 * t]     + bnsN[2 * t];
            oy += st * wnsN[2 * t + 1] + bnsN[2 * t + 1];
        }
        ((unsigned*)Xout)[(size_t)(gb + n) * 64 + t] =
            (unsigned)f2bf(ox) | ((unsigned)f2bf(oy) << 16);
    }
}

// ---------------- head ----------------

__global__ __launch_bounds__(128) void sum_nodes_kernel(const unsigned short* __restrict__ X, float* state_emb) {
    int cx = blockIdx.x, b = blockIdx.y, d = threadIdx.x;
    int n0 = cx * 157, n1 = n0 + 157;
    if (n1 > N_NODES) n1 = N_NODES;
    float acc = 0.f;
    for (int n = n0; n < n1; n++) acc += bf2f(X[(size_t)(b * N_NODES + n) * 128 + d]);
    atomicAdd(&state_emb[b * 128 + d], acc);
}

// ---------------- final: out = relu(X3@W2+b2).W3[128:] + c1[b] + b3 ; c1 inline ----------------

__global__ __launch_bounds__(256) void final_mfma(
    const unsigned short* __restrict__ X,
    const unsigned short* __restrict__ WThi, const unsigned short* __restrict__ WTlo,
    const float* __restrict__ b2, const float* __restrict__ W3,
    const float* __restrict__ b3,
    const float* __restrict__ state_emb, const float* __restrict__ W1,
    const float* __restrict__ b1,
    float* __restrict__ out)
{
    __shared__ float sB2[128], sW3[128];
    __shared__ float sPart[64 * 4];
    __shared__ float sC1p[8], sC1[4];

    int tid = threadIdx.x;
    int g0 = blockIdx.x * 64;
    int w = tid >> 6, lane = tid & 63;
    int quad = lane >> 4, mcol = lane & 15;

    if (tid < 128) { sB2[tid] = b2[tid]; sW3[tid] = W3[128 + tid]; }

    {
        int d = tid & 127;
        int bh = tid >> 7;   // half 0: b={0,2}; half 1: b={1,3}
        float p0 = b1[d], p1 = b1[d];
        for (int k = 0; k < 128; k++) {
            float wv = W1[k * 128 + d];
            p0 += state_emb[bh * 128 + k] * wv;
            p1 += state_emb[(bh + 2) * 128 + k] * wv;
        }
        float w3d = W3[d];
        p0 = fmaxf(p0, 0.f) * w3d;
        p1 = fmaxf(p1, 0.f) * w3d;
#pragma unroll
        for (int off = 1; off < 64; off <<= 1) {
            p0 += __shfl_xor(p0, off);
            p1 += __shfl_xor(p1, off);
        }
        if (lane == 0) { sC1p[w * 2 + 0] = p0; sC1p[w * 2 + 1] = p1; }
    }
    __syncthreads();
    if (tid == 0) {
        sC1[0] = sC1p[0] + sC1p[2];  sC1[2] = sC1p[1] + sC1p[3];
        sC1[1] = sC1p[4] + sC1p[6];  sC1[3] = sC1p[5] + sC1p[7];
    }

    float4v acc[4][2];
#pragma unroll
    for (int mt = 0; mt < 4; mt++)
#pragma unroll
        for (int nt = 0; nt < 2; nt++) acc[mt][nt] = (float4v){0.f, 0.f, 0.f, 0.f};

#pragma unroll 1
    for (int term = 0; term < 2; term++) {
        const unsigned short* WT = term ? WTlo : WThi;
        short8 Bf[4][2];
#pragma unroll
        for (int kc = 0; kc < 4; kc++)
#pragma unroll
            for (int nt = 0; nt < 2; nt++)
                Bf[kc][nt] = *(const short8*)(WT + (w * 32 + nt * 16 + mcol) * 128 + kc * 32 + quad * 8);
#pragma unroll
        for (int kc = 0; kc < 4; kc++) {
            short8 Aa[4];
#pragma unroll
            for (int mt = 0; mt < 4; mt++)
                Aa[mt] = *(const short8*)(X + (size_t)(g0 + mt * 16 + mcol) * 128 + kc * 32 + quad * 8);
#pragma unroll
            for (int mt = 0; mt < 4; mt++)
#pragma unroll
                for (int nt = 0; nt < 2; nt++)
                    acc[mt][nt] = __builtin_amdgcn_mfma_f32_16x16x32_bf16(Aa[mt], Bf[kc][nt], acc[mt][nt], 0, 0, 0);
        }
    }

    float pp[16];
#pragma unroll
    for (int r16 = 0; r16 < 16; r16++) pp[r16] = 0.f;
#pragma unroll
    for (int mt = 0; mt < 4; mt++)
#pragma unroll
        for (int nt = 0; nt < 2; nt++)
#pragma unroll
            for (int reg = 0; reg < 4; reg++) {
                int col = w * 32 + nt * 16 + mcol;
                float v = acc[mt][nt][reg] + sB2[col];
                v = v > 0.f ? v : 0.f;
                pp[mt * 4 + reg] += v * sW3[col];
            }
#pragma unroll
    for (int off = 1; off < 16; off <<= 1)
#pragma unroll
        for (int r16 = 0; r16 < 16; r16++)
            pp[r16] += __shfl_xor(pp[r16], off);
    if (mcol == 0) {
#pragma unroll
        for (int r16 = 0; r16 < 16; r16++) {
            int row = (r16 >> 2) * 16 + quad * 4 + (r16 & 3);
            sPart[row * 4 + w] = pp[r16];
        }
    }
    __syncthreads();
    if (tid < 64) {
        float p = sPart[tid * 4] + sPart[tid * 4 + 1] + sPart[tid * 4 + 2] + sPart[tid * 4 + 3];
        int g = g0 + tid;
        int b = g / N_NODES;
        out[g] = p + sC1[b] + b3[0];   // batch-major: out index == g
    }
}

// ---------------- launch ----------------

extern "C" void kernel_launch(void* const* d_in, const int* in_sizes, int n_in,
                              void* d_out, int out_size, void* d_ws, size_t ws_size,
                              hipStream_t stream) {
    const float* state    = (const float*)d_in[0];   // [B,N]
    const float* strucEmb = (const float*)d_in[1];   // [N,128]
    const int*   edge_idx = (const int*)d_in[2];     // [2,Etot]
    const float* gat_W    = (const float*)d_in[3];   // [3,128,128]
    const float* gat_aS   = (const float*)d_in[4];
    const float* gat_aD   = (const float*)d_in[5];
    const float* gat_Wns  = (const float*)d_in[6];
    const float* gat_bns  = (const float*)d_in[7];
    const float* gat_bias = (const float*)d_in[8];
    const float* W1 = (const float*)d_in[9];
    const float* b1 = (const float*)d_in[10];
    const float* W2 = (const float*)d_in[11];
    const float* b2 = (const float*)d_in[12];
    const float* W3 = (const float*)d_in[13];
    const float* b3 = (const float*)d_in[14];
    float* out = (float*)d_out;

    int Etot = in_sizes[2] / 2;
    const int* srcArr = edge_idx;
    const int* dstArr = edge_idx + Etot;

    float* ws = (float*)d_ws;
    unsigned short* Xb = (unsigned short*)ws;              // 5,120,000 us
    unsigned short* Hb = (unsigned short*)(ws + 2560000);  // 5,120,000 us
    float* aSrcP       = ws + 5120000;                     // 40,000 f
    float* aDstP       = ws + 5160000;                     // 40,000 f
    float* state_emb   = ws + 5200000;                     // 512 f
    unsigned short* whi = (unsigned short*)(ws + 5200516); // 65,536 us
    unsigned short* wlo = whi + 4 * 16384;                 // 65,536 us
    int*   iws         = (int*)(ws + 5200516 + 65536);
    int*   rowOff      = iws;                              // N+1
    int*   deg         = iws + 10001;
    int*   cursor      = deg + 10000;
    int*   srcLst      = cursor + 10000;                   // Etot

    setup_kernel<<<2796, 256, 0, stream>>>(strucEmb, state, gat_Wns, gat_bns,
                                           gat_W, W2, Xb, whi, wlo, deg, cursor, state_emb);
    hist_kernel<<<(Etot + 255) / 256, 256, 0, stream>>>(dstArr, Etot, deg);
    scan_kernel<<<1, 1024, 0, stream>>>(deg, rowOff);
    scatter_kernel<<<(Etot + 255) / 256, 256, 0, stream>>>(srcArr, dstArr, Etot, rowOff, cursor, srcLst);

    for (int l = 0; l < 3; l++) {
        gemm_att_mfma<<<BN / 64, 256, 0, stream>>>(
            Xb, whi + (size_t)l * 16384, wlo + (size_t)l * 16384,
            gat_aS + l * 128, gat_aD + l * 128, Hb, aSrcP, aDstP);
        sm_agg_kernel<<<N_NODES, 256, 0, stream>>>(
            rowOff, srcLst, aSrcP, aDstP, Hb, gat_bias + l * 128,
            state, gat_Wns + (l + 1 < 3 ? (l + 1) * 128 : 0),
            gat_bns + (l + 1 < 3 ? (l + 1) * 128 : 0), (l < 2) ? 1 : 0, Xb);
    }

    sum_nodes_kernel<<<dim3(64, B_SZ), 128, 0, stream>>>(Xb, state_emb);
    final_mfma<<<BN / 64, 256, 0, stream>>>(Xb, whi + 3 * 16384, wlo + 3 * 16384,
                                            b2, W3, b3, state_emb, W1, b1, out);
}

// Round 10
// 318.534 us; speedup vs baseline: 1.0984x; 1.0041x over previous
//
#include <hip/hip_runtime.h>
#include <math.h>

#define N_NODES 10000
#define B_SZ 4
#define SLOPE 0.01f
#define BN (B_SZ * N_NODES)
#define PADK 136   // ushorts per LDS C-row (272B, 16B-aligned)

typedef __attribute__((ext_vector_type(8))) short short8;
typedef __attribute__((ext_vector_type(4))) float float4v;

__device__ __forceinline__ unsigned short f2bf(float f) {
    unsigned u = __builtin_bit_cast(unsigned, f);
    u += 0x7fffu + ((u >> 16) & 1u);   // RNE
    return (unsigned short)(u >> 16);
}
__device__ __forceinline__ float bf2f(unsigned short s) {
    unsigned u = ((unsigned)s) << 16;
    return __builtin_bit_cast(float, u);
}
__device__ __forceinline__ float bflo(unsigned u) { return __builtin_bit_cast(float, u << 16); }
__device__ __forceinline__ float bfhi(unsigned u) { return __builtin_bit_cast(float, u & 0xffff0000u); }

// All activations batch-major: row index g = b*N_NODES + n.

// ---------------- fused setup: prep0 (vectorized x8) + wconv + init ----------------

__global__ __launch_bounds__(256) void setup_kernel(
    const float* __restrict__ strucEmb, const float* __restrict__ state,
    const float* __restrict__ Wns0, const float* __restrict__ bns0,
    const float* __restrict__ gatW, const float* __restrict__ W2,
    unsigned short* __restrict__ XS,
    unsigned short* __restrict__ whi, unsigned short* __restrict__ wlo,
    int* deg, int* cursor, float* state_emb)
{
    int bx = blockIdx.x, tid = threadIdx.x;
    if (bx < 2500) {
        int base = (bx * 256 + tid) * 8;       // element index, 8 per thread, same row g
        int g = base >> 7, d0 = base & 127;
        int n = g - (g / N_NODES) * N_NODES;
        float st = state[g];
        const float* se = strucEmb + (size_t)n * 128 + d0;
        const float* wp = Wns0 + d0;
        const float* bp = bns0 + d0;
        short8 v;
#pragma unroll
        for (int j = 0; j < 8; j++)
            v[j] = (short)f2bf(se[j] + st * wp[j] + bp[j]);
        *(short8*)(XS + base) = v;
    } else if (bx < 2756) {
        int i = (bx - 2500) * 256 + tid;     // 0..65535
        int w = i >> 14, rem = i & 16383;
        int k = rem >> 7, c = rem & 127;
        const float* src = (w < 3) ? (gatW + (size_t)w * 16384) : W2;
        float v = src[k * 128 + c];
        unsigned short h = f2bf(v);
        whi[w * 16384 + c * 128 + k] = h;
        wlo[w * 16384 + c * 128 + k] = f2bf(v - bf2f(h));
    } else {
        int i = (bx - 2756) * 256 + tid;
        if (i < N_NODES) { deg[i] = 0; cursor[i] = 0; }
        if (i < 512) state_emb[i] = 0.f;
    }
}

// ---------------- CSR build ----------------

__global__ __launch_bounds__(256) void hist_kernel(const int* __restrict__ dst, int Etot, int* deg) {
    int e = blockIdx.x * 256 + threadIdx.x;
    if (e < Etot) atomicAdd(&deg[dst[e]], 1);
}

__global__ __launch_bounds__(1024) void scan_kernel(const int* __restrict__ deg, int* __restrict__ rowOff) {
    __shared__ int wsum[16];
    int tid = threadIdx.x;
    int lane = tid & 63, wid = tid >> 6;
    int base = tid * 10;
    int v[10]; int tot = 0;
#pragma unroll
    for (int j = 0; j < 10; j++) {
        int idx = base + j;
        int d = (idx < N_NODES) ? deg[idx] : 0;
        tot += d; v[j] = tot;
    }
    int incl = tot;
    for (int off = 1; off < 64; off <<= 1) {
        int t = __shfl_up(incl, off, 64);
        if (lane >= off) incl += t;
    }
    if (lane == 63) wsum[wid] = incl;
    __syncthreads();
    if (wid == 0) {
        int wv = (lane < 16) ? wsum[lane] : 0;
        for (int off = 1; off < 16; off <<= 1) {
            int t = __shfl_up(wv, off, 64);
            if (lane >= off) wv += t;
        }
        if (lane < 16) wsum[lane] = wv;
    }
    __syncthreads();
    int waveoff = (wid > 0) ? wsum[wid - 1] : 0;
    int excl = waveoff + incl - tot;
    if (tid == 0) rowOff[0] = 0;
#pragma unroll
    for (int j = 0; j < 10; j++) {
        int idx = base + j;
        if (idx < N_NODES) rowOff[idx + 1] = excl + v[j];
    }
}

__global__ __launch_bounds__(256) void scatter_kernel(const int* __restrict__ src, const int* __restrict__ dst,
                                                      int Etot, const int* __restrict__ rowOff,
                                                      int* cursor, int* __restrict__ srcLst) {
    int e = blockIdx.x * 256 + threadIdx.x;
    if (e < Etot) {
        int d = dst[e];
        int pos = rowOff[d] + atomicAdd(&cursor[d], 1);
        srcLst[pos] = src[e];
    }
}

// ---------------- MFMA GEMM (GAT layer): H(bf16) = XS(bf16) @ W ; att dots ----------------

__global__ __launch_bounds__(256) void gemm_att_mfma(
    const unsigned short* __restrict__ XS,
    const unsigned short* __restrict__ WThi, const unsigned short* __restrict__ WTlo,
    const float* __restrict__ attS, const float* __restrict__ attD,
    unsigned short* __restrict__ Hout, float* __restrict__ aSrcP, float* __restrict__ aDstP)
{
    __shared__ __align__(16) unsigned short sCus[64 * PADK];
    __shared__ float sAs[128], sAd[128];
    __shared__ float sPart[64 * 8];

    int tid = threadIdx.x;
    int g0 = blockIdx.x * 64;
    int w = tid >> 6, lane = tid & 63;
    int quad = lane >> 4, mcol = lane & 15;

    if (tid < 128) { sAs[tid] = attS[tid]; sAd[tid] = attD[tid]; }

    float4v acc[4][2];
#pragma unroll
    for (int mt = 0; mt < 4; mt++)
#pragma unroll
        for (int nt = 0; nt < 2; nt++) acc[mt][nt] = (float4v){0.f, 0.f, 0.f, 0.f};

#pragma unroll 1
    for (int term = 0; term < 2; term++) {
        const unsigned short* WT = term ? WTlo : WThi;
        short8 Bf[4][2];
#pragma unroll
        for (int kc = 0; kc < 4; kc++)
#pragma unroll
            for (int nt = 0; nt < 2; nt++)
                Bf[kc][nt] = *(const short8*)(WT + (w * 32 + nt * 16 + mcol) * 128 + kc * 32 + quad * 8);
#pragma unroll
        for (int kc = 0; kc < 4; kc++) {
            short8 Aa[4];
#pragma unroll
            for (int mt = 0; mt < 4; mt++)
                Aa[mt] = *(const short8*)(XS + (size_t)(g0 + mt * 16 + mcol) * 128 + kc * 32 + quad * 8);
#pragma unroll
            for (int mt = 0; mt < 4; mt++)
#pragma unroll
                for (int nt = 0; nt < 2; nt++)
                    acc[mt][nt] = __builtin_amdgcn_mfma_f32_16x16x32_bf16(Aa[mt], Bf[kc][nt], acc[mt][nt], 0, 0, 0);
        }
    }

    __syncthreads();   // sAs/sAd visible

    float pp[16], pd[16];
#pragma unroll
    for (int r16 = 0; r16 < 16; r16++) { pp[r16] = 0.f; pd[r16] = 0.f; }
#pragma unroll
    for (int mt = 0; mt < 4; mt++)
#pragma unroll
        for (int nt = 0; nt < 2; nt++)
#pragma unroll
            for (int reg = 0; reg < 4; reg++) {
                int row = mt * 16 + quad * 4 + reg;   // C/D: col=lane&15, row=quad*4+reg
                int col = w * 32 + nt * 16 + mcol;
                float v = acc[mt][nt][reg];
                sCus[row * PADK + col] = f2bf(v);
                pp[mt * 4 + reg] += v * sAs[col];
                pd[mt * 4 + reg] += v * sAd[col];
            }
#pragma unroll
    for (int off = 1; off < 16; off <<= 1)
#pragma unroll
        for (int r16 = 0; r16 < 16; r16++) {
            pp[r16] += __shfl_xor(pp[r16], off);
            pd[r16] += __shfl_xor(pd[r16], off);
        }
    if (mcol == 0) {
#pragma unroll
        for (int r16 = 0; r16 < 16; r16++) {
            int row = (r16 >> 2) * 16 + quad * 4 + (r16 & 3);
            sPart[row * 8 + w * 2 + 0] = pp[r16];
            sPart[row * 8 + w * 2 + 1] = pd[r16];
        }
    }
    __syncthreads();

    for (int i = tid; i < 64 * 16; i += 256) {
        int r = i >> 4, c8 = i & 15;
        uint4 u = *(uint4*)(sCus + r * PADK + c8 * 8);
        *(uint4*)(Hout + (size_t)(g0 + r) * 128 + c8 * 8) = u;
    }
    if (tid < 64) {
        float s0 = sPart[tid * 8] + sPart[tid * 8 + 2] + sPart[tid * 8 + 4] + sPart[tid * 8 + 6];
        float s1 = sPart[tid * 8 + 1] + sPart[tid * 8 + 3] + sPart[tid * 8 + 5] + sPart[tid * 8 + 7];
        aSrcP[g0 + tid] = s0;
        aDstP[g0 + tid] = s1;
    }
}

// ---------------- fused softmax + aggregate (+ next-layer Wns/bns), bf16 in/out ----------------
// Flat grid of 10000 blocks; (batch, node-chunk) from blockIdx.x for XCD L2 locality (bijective).
// Pipelined gather: aSrcP issued as the OLDEST vmem load, then h0..h2 of batch 0 issued
// BEFORE the softmax shfl chain -> compiler waits vmcnt(3) for aSrcP, keeping h0..h2 in
// flight under the whole max/sum/exp chain. h3/h4 issue post-chain. VGPR held <=64.

__global__ __launch_bounds__(256) void sm_agg_kernel(
    const int* __restrict__ rowOff, const int* __restrict__ srcLst,
    const float* __restrict__ aSrcP, const float* __restrict__ aDstP,
    const unsigned short* __restrict__ H,
    const float* __restrict__ bias,
    const float* __restrict__ state, const float* __restrict__ wnsN,
    const float* __restrict__ bnsN, int addNext,
    unsigned short* __restrict__ Xout)
{
    __shared__ int   sSrcB[4 * 80];
    __shared__ float sAeB[4 * 80];
    int tid = threadIdx.x;
    int w = tid >> 6, t = tid & 63;
    int blk = blockIdx.x;
    int xcd = blk & 7;
    int b = xcd >> 1;
    int n = (((xcd & 1) * (N_NODES / 8) + (blk >> 3)) << 2) + w;
    int gb = b * N_NODES;
    int start = rowOff[n], end = rowOff[n + 1];
    int cnt = end - start;
    float adst = aDstP[gb + n];
    int*   sSrc = sSrcB + w * 80;
    float* sAe  = sAeB + w * 80;
    const uint4* H4 = (const uint4*)H;   // 16 uint4 per 128-bf16 row

    if (cnt <= 64) {
        int sn = n;
        if (t < cnt) sn = srcLst[start + t];
        sSrc[t] = sn;                       // pad lanes write self-row n
        if (t < 16) { sSrc[64 + t] = n; }   // pad slots 64..79

        float av = aSrcP[gb + sn];          // oldest outstanding vmem load

        int esub = t >> 4, c16 = t & 15;
        int j0 = esub, j1 = 4 + esub, j2 = 8 + esub;
        // issue first 3 H loads of batch 0 BEFORE the softmax chain
        uint4 h0 = H4[(size_t)(gb + sSrc[j0]) * 16 + c16];
        uint4 h1 = H4[(size_t)(gb + sSrc[j1]) * 16 + c16];
        uint4 h2 = H4[(size_t)(gb + sSrc[j2]) * 16 + c16];

        // softmax chain — waits only for av, h0..h2 stay in flight
        float vv = av + adst;
        float ae = (t < cnt) ? (vv > 0.f ? vv : SLOPE * vv) : -1e30f;
        float m = ae;
        m = fmaxf(m, __shfl_xor(m, 1));  m = fmaxf(m, __shfl_xor(m, 2));
        m = fmaxf(m, __shfl_xor(m, 4));  m = fmaxf(m, __shfl_xor(m, 8));
        m = fmaxf(m, __shfl_xor(m, 16)); m = fmaxf(m, __shfl_xor(m, 32));
        float e = (t < cnt) ? __expf(ae - m) : 0.f;
        float s = e;
        s += __shfl_xor(s, 1);  s += __shfl_xor(s, 2);  s += __shfl_xor(s, 4);
        s += __shfl_xor(s, 8);  s += __shfl_xor(s, 16); s += __shfl_xor(s, 32);
        float inv = 1.f / s;
        sAe[t] = (t < cnt) ? e * inv : 0.f;
        if (t < 16) sAe[64 + t] = 0.f;

        float a0 = 0.f, a1 = 0.f, a2 = 0.f, a3 = 0.f, a4 = 0.f, a5 = 0.f, a6 = 0.f, a7 = 0.f;

        {   // finish batch 0: issue h3/h4, consume all 5
            int j3 = 12 + esub, j4 = 16 + esub;
            uint4 h3 = H4[(size_t)(gb + sSrc[j3]) * 16 + c16];
            uint4 h4 = H4[(size_t)(gb + sSrc[j4]) * 16 + c16];
            float l0 = sAe[j0], l1 = sAe[j1], l2 = sAe[j2], l3 = sAe[j3], l4 = sAe[j4];
            a0 += l0 * bflo(h0.x); a1 += l0 * bfhi(h0.x);
            a2 += l0 * bflo(h0.y); a3 += l0 * bfhi(h0.y);
            a4 += l0 * bflo(h0.z); a5 += l0 * bfhi(h0.z);
            a6 += l0 * bflo(h0.w); a7 += l0 * bfhi(h0.w);
            a0 += l1 * bflo(h1.x); a1 += l1 * bfhi(h1.x);
            a2 += l1 * bflo(h1.y); a3 += l1 * bfhi(h1.y);
            a4 += l1 * bflo(h1.z); a5 += l1 * bfhi(h1.z);
            a6 += l1 * bflo(h1.w); a7 += l1 * bfhi(h1.w);
            a0 += l2 * bflo(h2.x); a1 += l2 * bfhi(h2.x);
            a2 += l2 * bflo(h2.y); a3 += l2 * bfhi(h2.y);
            a4 += l2 * bflo(h2.z); a5 += l2 * bfhi(h2.z);
            a6 += l2 * bflo(h2.w); a7 += l2 * bfhi(h2.w);
            a0 += l3 * bflo(h3.x); a1 += l3 * bfhi(h3.x);
            a2 += l3 * bflo(h3.y); a3 += l3 * bfhi(h3.y);
            a4 += l3 * bflo(h3.z); a5 += l3 * bfhi(h3.z);
            a6 += l3 * bflo(h3.w); a7 += l3 * bfhi(h3.w);
            a0 += l4 * bflo(h4.x); a1 += l4 * bfhi(h4.x);
            a2 += l4 * bflo(h4.y); a3 += l4 * bfhi(h4.y);
            a4 += l4 * bflo(h4.z); a5 += l4 * bfhi(h4.z);
            a6 += l4 * bflo(h4.w); a7 += l4 * bfhi(h4.w);
        }

        int nb = (cnt + 19) / 20;   // remaining batches of 20 edges
#pragma unroll 1
        for (int bb = 1; bb < nb; bb++) {
            int j = bb * 20;
            int j0b = j + esub, j1b = j + 4 + esub, j2b = j + 8 + esub,
                j3b = j + 12 + esub, j4b = j + 16 + esub;
            uint4 g0v = H4[(size_t)(gb + sSrc[j0b]) * 16 + c16];
            uint4 g1v = H4[(size_t)(gb + sSrc[j1b]) * 16 + c16];
            uint4 g2v = H4[(size_t)(gb + sSrc[j2b]) * 16 + c16];
            uint4 g3v = H4[(size_t)(gb + sSrc[j3b]) * 16 + c16];
            uint4 g4v = H4[(size_t)(gb + sSrc[j4b]) * 16 + c16];
            float l0 = sAe[j0b], l1 = sAe[j1b], l2 = sAe[j2b], l3 = sAe[j3b], l4 = sAe[j4b];
            a0 += l0 * bflo(g0v.x); a1 += l0 * bfhi(g0v.x);
            a2 += l0 * bflo(g0v.y); a3 += l0 * bfhi(g0v.y);
            a4 += l0 * bflo(g0v.z); a5 += l0 * bfhi(g0v.z);
            a6 += l0 * bflo(g0v.w); a7 += l0 * bfhi(g0v.w);
            a0 += l1 * bflo(g1v.x); a1 += l1 * bfhi(g1v.x);
            a2 += l1 * bflo(g1v.y); a3 += l1 * bfhi(g1v.y);
            a4 += l1 * bflo(g1v.z); a5 += l1 * bfhi(g1v.z);
            a6 += l1 * bflo(g1v.w); a7 += l1 * bfhi(g1v.w);
            a0 += l2 * bflo(g2v.x); a1 += l2 * bfhi(g2v.x);
            a2 += l2 * bflo(g2v.y); a3 += l2 * bfhi(g2v.y);
            a4 += l2 * bflo(g2v.z); a5 += l2 * bfhi(g2v.z);
            a6 += l2 * bflo(g2v.w); a7 += l2 * bfhi(g2v.w);
            a0 += l3 * bflo(g3v.x); a1 += l3 * bfhi(g3v.x);
            a2 += l3 * bflo(g3v.y); a3 += l3 * bfhi(g3v.y);
            a4 += l3 * bflo(g3v.z); a5 += l3 * bfhi(g3v.z);
            a6 += l3 * bflo(g3v.w); a7 += l3 * bfhi(g3v.w);
            a0 += l4 * bflo(g4v.x); a1 += l4 * bfhi(g4v.x);
            a2 += l4 * bflo(g4v.y); a3 += l4 * bfhi(g4v.y);
            a4 += l4 * bflo(g4v.z); a5 += l4 * bfhi(g4v.z);
            a6 += l4 * bflo(g4v.w); a7 += l4 * bfhi(g4v.w);
        }

        a0 += __shfl_xor(a0, 16); a1 += __shfl_xor(a1, 16);
        a2 += __shfl_xor(a2, 16); a3 += __shfl_xor(a3, 16);
        a4 += __shfl_xor(a4, 16); a5 += __shfl_xor(a5, 16);
        a6 += __shfl_xor(a6, 16); a7 += __shfl_xor(a7, 16);
        a0 += __shfl_xor(a0, 32); a1 += __shfl_xor(a1, 32);
        a2 += __shfl_xor(a2, 32); a3 += __shfl_xor(a3, 32);
        a4 += __shfl_xor(a4, 32); a5 += __shfl_xor(a5, 32);
        a6 += __shfl_xor(a6, 32); a7 += __shfl_xor(a7, 32);
        if (esub == 0) {
            int d0 = c16 * 8;
            float o0 = fmaxf(a0 + bias[d0],     0.f);
            float o1 = fmaxf(a1 + bias[d0 + 1], 0.f);
            float o2 = fmaxf(a2 + bias[d0 + 2], 0.f);
            float o3 = fmaxf(a3 + bias[d0 + 3], 0.f);
            float o4 = fmaxf(a4 + bias[d0 + 4], 0.f);
            float o5 = fmaxf(a5 + bias[d0 + 5], 0.f);
            float o6 = fmaxf(a6 + bias[d0 + 6], 0.f);
            float o7 = fmaxf(a7 + bias[d0 + 7], 0.f);
            if (addNext) {
                float st = state[gb + n];
                o0 += st * wnsN[d0]     + bnsN[d0];
                o1 += st * wnsN[d0 + 1] + bnsN[d0 + 1];
                o2 += st * wnsN[d0 + 2] + bnsN[d0 + 2];
                o3 += st * wnsN[d0 + 3] + bnsN[d0 + 3];
                o4 += st * wnsN[d0 + 4] + bnsN[d0 + 4];
                o5 += st * wnsN[d0 + 5] + bnsN[d0 + 5];
                o6 += st * wnsN[d0 + 6] + bnsN[d0 + 6];
                o7 += st * wnsN[d0 + 7] + bnsN[d0 + 7];
            }
            uint4 u;
            u.x = (unsigned)f2bf(o0) | ((unsigned)f2bf(o1) << 16);
            u.y = (unsigned)f2bf(o2) | ((unsigned)f2bf(o3) << 16);
            u.z = (unsigned)f2bf(o4) | ((unsigned)f2bf(o5) << 16);
            u.w = (unsigned)f2bf(o6) | ((unsigned)f2bf(o7) << 16);
            ((uint4*)Xout)[(size_t)(gb + n) * 16 + c16] = u;
        }
    } else {
        // fallback (deg > 64, rare) — per-wave LDS, no barriers needed
        const unsigned* Hu = (const unsigned*)H;
        float m = -1e30f;
        for (int i = start + t; i < end; i += 64) {
            int sn = srcLst[i];
            float v = aSrcP[gb + sn] + adst;
            m = fmaxf(m, v > 0.f ? v : SLOPE * v);
        }
        m = fmaxf(m, __shfl_xor(m, 1));  m = fmaxf(m, __shfl_xor(m, 2));
        m = fmaxf(m, __shfl_xor(m, 4));  m = fmaxf(m, __shfl_xor(m, 8));
        m = fmaxf(m, __shfl_xor(m, 16)); m = fmaxf(m, __shfl_xor(m, 32));
        float s = 0.f;
        for (int i = start + t; i < end; i += 64) {
            int sn = srcLst[i];
            float v = aSrcP[gb + sn] + adst;
            float ae2 = v > 0.f ? v : SLOPE * v;
            s += __expf(ae2 - m);
        }
        s += __shfl_xor(s, 1);  s += __shfl_xor(s, 2);  s += __shfl_xor(s, 4);
        s += __shfl_xor(s, 8);  s += __shfl_xor(s, 16); s += __shfl_xor(s, 32);
        float inv = 1.f / s;
        float accx = 0.f, accy = 0.f;
        for (int c0 = start; c0 < end; c0 += 64) {
            int c = min(64, end - c0);
            if (t < c) {
                int sn = srcLst[c0 + t];
                sSrc[t] = sn;
                float v = aSrcP[gb + sn] + adst;
                float ae2 = v > 0.f ? v : SLOPE * v;
                sAe[t] = __expf(ae2 - m);
            }
            for (int j = 0; j < c; j++) {
                float a0 = sAe[j];
                unsigned h0 = Hu[(size_t)(gb + sSrc[j]) * 64 + t];
                accx += a0 * bflo(h0);
                accy += a0 * bfhi(h0);
            }
        }
        float ox = fmaxf(accx * inv + bias[2 * t], 0.f);
        float oy = fmaxf(accy * inv + bias[2 * t + 1], 0.f);
        if (addNext) {
            float st = state[gb + n];
            ox += st * wnsN[2 * t]     + bnsN[2 * t];
            oy += st * wnsN[2 * t + 1] + bnsN[2 * t + 1];
        }
        ((unsigned*)Xout)[(size_t)(gb + n) * 64 + t] =
            (unsigned)f2bf(ox) | ((unsigned)f2bf(oy) << 16);
    }
}

// ---------------- head ----------------

__global__ __launch_bounds__(128) void sum_nodes_kernel(const unsigned short* __restrict__ X, float* state_emb) {
    int cx = blockIdx.x, b = blockIdx.y, d = threadIdx.x;
    int n0 = cx * 157, n1 = n0 + 157;
    if (n1 > N_NODES) n1 = N_NODES;
    float acc = 0.f;
    for (int n = n0; n < n1; n++) acc += bf2f(X[(size_t)(b * N_NODES + n) * 128 + d]);
    atomicAdd(&state_emb[b * 128 + d], acc);
}

// ---------------- final: out = relu(X3@W2+b2).W3[128:] + c1[b] + b3 ; c1 inline ----------------

__global__ __launch_bounds__(256) void final_mfma(
    const unsigned short* __restrict__ X,
    const unsigned short* __restrict__ WThi, const unsigned short* __restrict__ WTlo,
    const float* __restrict__ b2, const float* __restrict__ W3,
    const float* __restrict__ b3,
    const float* __restrict__ state_emb, const float* __restrict__ W1,
    const float* __restrict__ b1,
    float* __restrict__ out)
{
    __shared__ float sB2[128], sW3[128];
    __shared__ float sPart[64 * 4];
    __shared__ float sC1p[8], sC1[4];

    int tid = threadIdx.x;
    int g0 = blockIdx.x * 64;
    int w = tid >> 6, lane = tid & 63;
    int quad = lane >> 4, mcol = lane & 15;

    if (tid < 128) { sB2[tid] = b2[tid]; sW3[tid] = W3[128 + tid]; }

    {
        int d = tid & 127;
        int bh = tid >> 7;   // half 0: b={0,2}; half 1: b={1,3}
        float p0 = b1[d], p1 = b1[d];
        for (int k = 0; k < 128; k++) {
            float wv = W1[k * 128 + d];
            p0 += state_emb[bh * 128 + k] * wv;
            p1 += state_emb[(bh + 2) * 128 + k] * wv;
        }
        float w3d = W3[d];
        p0 = fmaxf(p0, 0.f) * w3d;
        p1 = fmaxf(p1, 0.f) * w3d;
#pragma unroll
        for (int off = 1; off < 64; off <<= 1) {
            p0 += __shfl_xor(p0, off);
            p1 += __shfl_xor(p1, off);
        }
        if (lane == 0) { sC1p[w * 2 + 0] = p0; sC1p[w * 2 + 1] = p1; }
    }
    __syncthreads();
    if (tid == 0) {
        sC1[0] = sC1p[0] + sC1p[2];  sC1[2] = sC1p[1] + sC1p[3];
        sC1[1] = sC1p[4] + sC1p[6];  sC1[3] = sC1p[5] + sC1p[7];
    }

    float4v acc[4][2];
#pragma unroll
    for (int mt = 0; mt < 4; mt++)
#pragma unroll
        for (int nt = 0; nt < 2; nt++) acc[mt][nt] = (float4v){0.f, 0.f, 0.f, 0.f};

#pragma unroll 1
    for (int term = 0; term < 2; term++) {
        const unsigned short* WT = term ? WTlo : WThi;
        short8 Bf[4][2];
#pragma unroll
        for (int kc = 0; kc < 4; kc++)
#pragma unroll
            for (int nt = 0; nt < 2; nt++)
                Bf[kc][nt] = *(const short8*)(WT + (w * 32 + nt * 16 + mcol) * 128 + kc * 32 + quad * 8);
#pragma unroll
        for (int kc = 0; kc < 4; kc++) {
            short8 Aa[4];
#pragma unroll
            for (int mt = 0; mt < 4; mt++)
                Aa[mt] = *(const short8*)(X + (size_t)(g0 + mt * 16 + mcol) * 128 + kc * 32 + quad * 8);
#pragma unroll
            for (int mt = 0; mt < 4; mt++)
#pragma unroll
                for (int nt = 0; nt < 2; nt++)
                    acc[mt][nt] = __builtin_amdgcn_mfma_f32_16x16x32_bf16(Aa[mt], Bf[kc][nt], acc[mt][nt], 0, 0, 0);
        }
    }

    float pp[16];
#pragma unroll
    for (int r16 = 0; r16 < 16; r16++) pp[r16] = 0.f;
#pragma unroll
    for (int mt = 0; mt < 4; mt++)
#pragma unroll
        for (int nt = 0; nt < 2; nt++)
#pragma unroll
            for (int reg = 0; reg < 4; reg++) {
                int col = w * 32 + nt * 16 + mcol;
                float v = acc[mt][nt][reg] + sB2[col];
                v = v > 0.f ? v : 0.f;
                pp[mt * 4 + reg] += v * sW3[col];
            }
#pragma unroll
    for (int off = 1; off < 16; off <<= 1)
#pragma unroll
        for (int r16 = 0; r16 < 16; r16++)
            pp[r16] += __shfl_xor(pp[r16], off);
    if (mcol == 0) {
#pragma unroll
        for (int r16 = 0; r16 < 16; r16++) {
            int row = (r16 >> 2) * 16 + quad * 4 + (r16 & 3);
            sPart[row * 4 + w] = pp[r16];
        }
    }
    __syncthreads();
    if (tid < 64) {
        float p = sPart[tid * 4] + sPart[tid * 4 + 1] + sPart[tid * 4 + 2] + sPart[tid * 4 + 3];
        int g = g0 + tid;
        int b = g / N_NODES;
        out[g] = p + sC1[b] + b3[0];   // batch-major: out index == g
    }
}

// ---------------- launch ----------------

extern "C" void kernel_launch(void* const* d_in, const int* in_sizes, int n_in,
                              void* d_out, int out_size, void* d_ws, size_t ws_size,
                              hipStream_t stream) {
    const float* state    = (const float*)d_in[0];   // [B,N]
    const float* strucEmb = (const float*)d_in[1];   // [N,128]
    const int*   edge_idx = (const int*)d_in[2];     // [2,Etot]
    const float* gat_W    = (const float*)d_in[3];   // [3,128,128]
    const float* gat_aS   = (const float*)d_in[4];
    const float* gat_aD   = (const float*)d_in[5];
    const float* gat_Wns  = (const float*)d_in[6];
    const float* gat_bns  = (const float*)d_in[7];
    const float* gat_bias = (const float*)d_in[8];
    const float* W1 = (const float*)d_in[9];
    const float* b1 = (const float*)d_in[10];
    const float* W2 = (const float*)d_in[11];
    const float* b2 = (const float*)d_in[12];
    const float* W3 = (const float*)d_in[13];
    const float* b3 = (const float*)d_in[14];
    float* out = (float*)d_out;

    int Etot = in_sizes[2] / 2;
    const int* srcArr = edge_idx;
    const int* dstArr = edge_idx + Etot;

    float* ws = (float*)d_ws;
    unsigned short* Xb = (unsigned short*)ws;              // 5,120,000 us
    unsigned short* Hb = (unsigned short*)(ws + 2560000);  // 5,120,000 us
    float* aSrcP       = ws + 5120000;                     // 40,000 f
    float* aDstP       = ws + 5160000;                     // 40,000 f
    float* state_emb   = ws + 5200000;                     // 512 f
    unsigned short* whi = (unsigned short*)(ws + 5200516); // 65,536 us
    unsigned short* wlo = whi + 4 * 16384;                 // 65,536 us
    int*   iws         = (int*)(ws + 5200516 + 65536);
    int*   rowOff      = iws;                              // N+1
    int*   deg         = iws + 10001;
    int*   cursor      = deg + 10000;
    int*   srcLst      = cursor + 10000;                   // Etot

    setup_kernel<<<2796, 256, 0, stream>>>(strucEmb, state, gat_Wns, gat_bns,
                                           gat_W, W2, Xb, whi, wlo, deg, cursor, state_emb);
    hist_kernel<<<(Etot + 255) / 256, 256, 0, stream>>>(dstArr, Etot, deg);
    scan_kernel<<<1, 1024, 0, stream>>>(deg, rowOff);
    scatter_kernel<<<(Etot + 255) / 256, 256, 0, stream>>>(srcArr, dstArr, Etot, rowOff, cursor, srcLst);

    for (int l = 0; l < 3; l++) {
        gemm_att_mfma<<<BN / 64, 256, 0, stream>>>(
            Xb, whi + (size_t)l * 16384, wlo + (size_t)l * 16384,
            gat_aS + l * 128, gat_aD + l * 128, Hb, aSrcP, aDstP);
        sm_agg_kernel<<<N_NODES, 256, 0, stream>>>(
            rowOff, srcLst, aSrcP, aDstP, Hb, gat_bias + l * 128,
            state, gat_Wns + (l + 1 < 3 ? (l + 1) * 128 : 0),
            gat_bns + (l + 1 < 3 ? (l + 1) * 128 : 0), (l < 2) ? 1 : 0, Xb);
    }

    sum_nodes_kernel<<<dim3(64, B_SZ), 128, 0, stream>>>(Xb, state_emb);
    final_mfma<<<BN / 64, 256, 0, stream>>>(Xb, whi + 3 * 16384, wlo + 3 * 16384,
                                            b2, W3, b3, state_emb, W1, b1, out);
}